// Round 1
// baseline (478.394 us; speedup 1.0000x reference)
//
#include <hip/hip_runtime.h>

typedef unsigned short u16;
typedef unsigned int u32;
typedef __attribute__((ext_vector_type(8))) short short8;
typedef __attribute__((ext_vector_type(8))) unsigned short u16x8;
typedef __attribute__((ext_vector_type(4))) float f32x4;

__device__ __forceinline__ u16 f2bf(float f){
  u32 u = __builtin_bit_cast(u32, f);
  u32 r = u + 0x7FFFu + ((u >> 16) & 1u);
  return (u16)(r >> 16);
}
__device__ __forceinline__ float bf2f(u16 h){
  u32 u = ((u32)h) << 16;
  return __builtin_bit_cast(float, u);
}

__device__ __forceinline__ void gld_lds16(const u16* g, u16* l){
  __builtin_amdgcn_global_load_lds(
      (const __attribute__((address_space(1))) u32*)g,
      (__attribute__((address_space(3))) u32*)l, 16, 0, 0);
}

#define MFMA(a,b,c) __builtin_amdgcn_mfma_f32_16x16x32_bf16((a),(b),(c),0,0,0)

// ---------------- cast x (f32 -> bf16), 8 elems/thread ----------------
__global__ void k_cast_x(const float* __restrict__ in, u16* __restrict__ out, int n8){
  int i = blockIdx.x*256 + threadIdx.x;
  if (i >= n8) return;
  const float4 a = ((const float4*)in)[2*i];
  const float4 b = ((const float4*)in)[2*i+1];
  u16x8 o;
  o[0]=f2bf(a.x); o[1]=f2bf(a.y); o[2]=f2bf(a.z); o[3]=f2bf(a.w);
  o[4]=f2bf(b.x); o[5]=f2bf(b.y); o[6]=f2bf(b.z); o[7]=f2bf(b.w);
  ((u16x8*)out)[i] = o;
}

// ---------------- transpose + cast: in[R][C] f32 -> out[C][R] bf16 ----------------
__global__ void k_transpose_cast(const float* __restrict__ in, u16* __restrict__ out,
                                 int R, int C){
  __shared__ float tile[32][33];
  int c0 = blockIdx.x*32, r0 = blockIdx.y*32;
  int tx = threadIdx.x, ty = threadIdx.y; // block (32,8)
  #pragma unroll
  for (int i=0;i<4;i++) tile[ty+8*i][tx] = in[(size_t)(r0+ty+8*i)*C + c0+tx];
  __syncthreads();
  #pragma unroll
  for (int i=0;i<4;i++) out[(size_t)(c0+ty+8*i)*R + r0+tx] = f2bf(tile[tx][ty+8*i]);
}

// ---------------- GEMM: C[M][N] = A[M][K](bf16) * Bt[N][K](bf16) + bias[N] ----------------
// 128x128 tile, BK=32, 4 waves, m97 structure with global_load_lds width-16.
template<int OUT_BF16>
__global__ __launch_bounds__(256) void gemm_bt(const u16* __restrict__ A,
                                               const u16* __restrict__ Bt,
                                               const float* __restrict__ bias,
                                               void* __restrict__ Cp,
                                               int M, int N, int K){
  __shared__ __align__(16) u16 As[128*32];
  __shared__ __align__(16) u16 Bs[128*32];
  int tid = threadIdx.x, lane = tid&63, wv = tid>>6;
  int wr = wv>>1, wc = wv&1;
  int lr16 = lane&15, lg = lane>>4;
  size_t brow = (size_t)blockIdx.y*128, bcol = (size_t)blockIdx.x*128;
  f32x4 acc[4][4] = {};
  int nk = K>>5;
  for (int kt=0; kt<nk; ++kt){
    int k0 = kt*32;
    #pragma unroll
    for (int c=0;c<2;c++){
      gld_lds16(A  + (brow + c*64 + (tid>>2))*K + k0 + (tid&3)*8, &As[c*2048 + tid*8]);
      gld_lds16(Bt + (bcol + c*64 + (tid>>2))*K + k0 + (tid&3)*8, &Bs[c*2048 + tid*8]);
    }
    __syncthreads();
    short8 af[4], bfr[4];
    #pragma unroll
    for (int m=0;m<4;m++) af[m]  = *(const short8*)&As[(wr*64 + m*16 + lr16)*32 + lg*8];
    #pragma unroll
    for (int n=0;n<4;n++) bfr[n] = *(const short8*)&Bs[(wc*64 + n*16 + lr16)*32 + lg*8];
    #pragma unroll
    for (int m=0;m<4;m++)
      #pragma unroll
      for (int n=0;n<4;n++) acc[m][n] = MFMA(af[m], bfr[n], acc[m][n]);
    __syncthreads();
  }
  // epilogue
  #pragma unroll
  for (int n=0;n<4;n++){
    size_t col = bcol + wc*64 + n*16 + lr16;
    float bs = bias[col];
    #pragma unroll
    for (int m=0;m<4;m++)
      #pragma unroll
      for (int j=0;j<4;j++){
        size_t row = brow + wr*64 + m*16 + lg*4 + j;
        float v = acc[m][n][j] + bs;
        if (OUT_BF16) ((u16*)Cp)[row*(size_t)N + col] = f2bf(v);
        else          ((float*)Cp)[row*(size_t)N + col] = v;
      }
  }
}

// ---------------- flash attention, causal, hs=64, H=16 ----------------
// Block: 4 waves, 64 q-rows (16/wave), KVBLK=32. Swapped QK^T so each lane
// holds a full q-row slice of S^T (softmax reduce = 2 shfl_xor).
__global__ __launch_bounds__(256) void k_attn(const u16* __restrict__ qkv,
                                              u16* __restrict__ o, int T){
  __shared__ __align__(16) u16 Ks[32*64];
  __shared__ __align__(16) u16 VT[64*32];
  __shared__ __align__(16) u16 Pl[4][16*32];
  int tid = threadIdx.x, lane = tid&63, wv = tid>>6;
  int qt = blockIdx.x, bh = blockIdx.y;
  int b = bh>>4, h = bh&15;
  size_t bt0 = (size_t)b*T;
  int qbase = qt*64;
  int lr16 = lane&15, lg = lane>>4;

  // Q fragments (B-operand of swapped QK^T): col q = lane&15, d = lg*8 (+32)
  short8 qf[2];
  {
    const u16* qp = qkv + (bt0 + qbase + wv*16 + lr16)*3072 + h*192 + lg*8;
    #pragma unroll
    for (int t=0;t<2;t++){
      u16x8 v = *(const u16x8*)(qp + t*32);
      #pragma unroll
      for (int j=0;j<8;j++) v[j] = f2bf(bf2f(v[j])*0.125f); // exact (pow2)
      qf[t] = __builtin_bit_cast(short8, v);
    }
  }
  f32x4 O[4] = {{0,0,0,0},{0,0,0,0},{0,0,0,0},{0,0,0,0}};
  float m_run = -1e30f, l_run = 0.f;
  int qg = qbase + wv*16 + lr16;
  int nkv = (qbase + 64) >> 5;
  for (int kb=0; kb<nkv; ++kb){
    int kv0 = kb*32;
    { // stage K (linear -> global_load_lds), V transposed via regs
      int r = tid>>3, c8 = (tid&7)*8;
      const u16* kp = qkv + (bt0 + kv0 + r)*3072 + h*192 + 64 + c8;
      gld_lds16(kp, &Ks[r*64 + c8]);
      u16x8 vvv = *(const u16x8*)(qkv + (bt0 + kv0 + r)*3072 + h*192 + 128 + c8);
      #pragma unroll
      for (int j=0;j<8;j++) VT[(c8+j)*32 + r] = vvv[j];
    }
    __syncthreads();
    // S^T[kv][q] = sum_d K[kv][d] * Q[q][d]
    f32x4 st[2];
    #pragma unroll
    for (int kvh=0;kvh<2;kvh++){
      short8 kf0 = *(const short8*)&Ks[(kvh*16 + lr16)*64 + lg*8];
      short8 kf1 = *(const short8*)&Ks[(kvh*16 + lr16)*64 + 32 + lg*8];
      f32x4 z = {0,0,0,0};
      z = MFMA(kf0, qf[0], z);
      z = MFMA(kf1, qf[1], z);
      st[kvh] = z;
    }
    // causal mask + row max (lane holds q = lane&15, kv = kv0+kvh*16+lg*4+j)
    float mx = -1e30f;
    #pragma unroll
    for (int kvh=0;kvh<2;kvh++)
      #pragma unroll
      for (int j=0;j<4;j++){
        int kvg = kv0 + kvh*16 + lg*4 + j;
        float s = (kvg <= qg) ? st[kvh][j] : -1e30f;
        st[kvh][j] = s;
        mx = fmaxf(mx, s);
      }
    mx = fmaxf(mx, __shfl_xor(mx, 16));
    mx = fmaxf(mx, __shfl_xor(mx, 32));
    float m_new = fmaxf(m_run, mx);
    float alpha = __expf(m_run - m_new);
    float ps = 0.f;
    u32 pw[4];
    #pragma unroll
    for (int kvh=0;kvh<2;kvh++){
      float p0 = __expf(st[kvh][0]-m_new), p1 = __expf(st[kvh][1]-m_new);
      float p2 = __expf(st[kvh][2]-m_new), p3 = __expf(st[kvh][3]-m_new);
      ps += (p0+p1)+(p2+p3);
      pw[kvh*2+0] = (u32)f2bf(p0) | ((u32)f2bf(p1)<<16);
      pw[kvh*2+1] = (u32)f2bf(p2) | ((u32)f2bf(p3)<<16);
    }
    ps += __shfl_xor(ps, 16);
    ps += __shfl_xor(ps, 32);
    l_run = l_run*alpha + ps;
    m_run = m_new;
    // repack P^T -> P[q][kv] in LDS (per-wave buffer)
    #pragma unroll
    for (int kvh=0;kvh<2;kvh++){
      u32* dst = (u32*)&Pl[wv][lr16*32 + kvh*16 + lg*4];
      dst[0] = pw[kvh*2]; dst[1] = pw[kvh*2+1];
    }
    // rescale O (rows q = lg*4+j need alpha from lane q)
    float arow[4];
    #pragma unroll
    for (int j=0;j<4;j++) arow[j] = __shfl(alpha, lg*4 + j);
    #pragma unroll
    for (int db=0;db<4;db++)
      #pragma unroll
      for (int j=0;j<4;j++) O[db][j] *= arow[j];
    // PV: O[q][d] += P[q][kv] * V[kv][d]
    short8 pa = *(const short8*)&Pl[wv][lr16*32 + lg*8];
    #pragma unroll
    for (int db=0;db<4;db++){
      short8 vf = *(const short8*)&VT[(db*16 + lr16)*32 + lg*8];
      O[db] = MFMA(pa, vf, O[db]);
    }
    __syncthreads();
  }
  float lrow[4];
  #pragma unroll
  for (int j=0;j<4;j++) lrow[j] = __shfl(l_run, lg*4 + j);
  #pragma unroll
  for (int db=0;db<4;db++)
    #pragma unroll
    for (int j=0;j<4;j++){
      size_t row = bt0 + qbase + wv*16 + lg*4 + j;
      o[row*1024 + h*64 + db*16 + lr16] = f2bf(O[db][j] / lrow[j]);
    }
}

extern "C" void kernel_launch(void* const* d_in, const int* in_sizes, int n_in,
                              void* d_out, int out_size, void* d_ws, size_t ws_size,
                              hipStream_t stream){
  (void)in_sizes; (void)n_in; (void)out_size; (void)ws_size;
  const float* x     = (const float*)d_in[0];
  const float* Wqkv  = (const float*)d_in[1];
  const float* bqkv  = (const float*)d_in[2];
  const float* Wproj = (const float*)d_in[3];
  const float* bproj = (const float*)d_in[4];
  float* out = (float*)d_out;
  const int B=4, T=2048, C=1024;
  const int M = B*T; // 8192
  char* ws = (char*)d_ws;
  u16* qkvb   = (u16*)(ws);                 // 8192*3072 bf16 = 50331648 B
  u16* attnb  = (u16*)(ws + 50331648);      // 8192*1024 bf16 = 16777216 B
  u16* xb     = (u16*)(ws + 67108864);      // 8192*1024 bf16 = 16777216 B
  u16* wqkvT  = (u16*)(ws + 83886080);      // 3072*1024 bf16 =  6291456 B
  u16* wprojT = (u16*)(ws + 90177536);      // 1024*1024 bf16 =  2097152 B

  k_cast_x<<<4096, 256, 0, stream>>>(x, xb, M*C/8);
  dim3 tb(32,8);
  k_transpose_cast<<<dim3(96,32), tb, 0, stream>>>(Wqkv, wqkvT, C, 3*C);
  k_transpose_cast<<<dim3(32,32), tb, 0, stream>>>(Wproj, wprojT, C, C);
  gemm_bt<1><<<dim3(24,64), 256, 0, stream>>>(xb, wqkvT, bqkv, qkvb, M, 3*C, C);
  k_attn<<<dim3(32,64), 256, 0, stream>>>(qkvb, attnb, T);
  gemm_bt<0><<<dim3(8,64), 256, 0, stream>>>(attnb, wprojT, bproj, out, M, C, C);
}

// Round 3
// 306.694 us; speedup vs baseline: 1.5598x; 1.5598x over previous
//
#include <hip/hip_runtime.h>

typedef unsigned short u16;
typedef unsigned int u32;
typedef __attribute__((ext_vector_type(8))) short short8;
typedef __attribute__((ext_vector_type(8))) unsigned short u16x8;
typedef __attribute__((ext_vector_type(2))) unsigned int u32x2;
typedef __attribute__((ext_vector_type(4))) float f32x4;

__device__ __forceinline__ u16 f2bf(float f){
  u32 u = __builtin_bit_cast(u32, f);
  u32 r = u + 0x7FFFu + ((u >> 16) & 1u);
  return (u16)(r >> 16);
}
__device__ __forceinline__ float bf2f(u16 h){
  u32 u = ((u32)h) << 16;
  return __builtin_bit_cast(float, u);
}

__device__ __forceinline__ void gld_lds16(const u16* g, u16* l){
  __builtin_amdgcn_global_load_lds(
      (const __attribute__((address_space(1))) u32*)g,
      (__attribute__((address_space(3))) u32*)l, 16, 0, 0);
}

#define MFMA(a,b,c) __builtin_amdgcn_mfma_f32_16x16x32_bf16((a),(b),(c),0,0,0)

// ---------------- cast x (f32 -> bf16), 8 elems/thread ----------------
__global__ void k_cast_x(const float* __restrict__ in, u16* __restrict__ out, int n8){
  int i = blockIdx.x*256 + threadIdx.x;
  if (i >= n8) return;
  const float4 a = ((const float4*)in)[2*i];
  const float4 b = ((const float4*)in)[2*i+1];
  u16x8 o;
  o[0]=f2bf(a.x); o[1]=f2bf(a.y); o[2]=f2bf(a.z); o[3]=f2bf(a.w);
  o[4]=f2bf(b.x); o[5]=f2bf(b.y); o[6]=f2bf(b.z); o[7]=f2bf(b.w);
  ((u16x8*)out)[i] = o;
}

// ---------------- transpose + cast: in[R][C] f32 -> out[C][R] bf16 ----------------
__global__ void k_transpose_cast(const float* __restrict__ in, u16* __restrict__ out,
                                 int R, int C){
  __shared__ float tile[32][33];
  int c0 = blockIdx.x*32, r0 = blockIdx.y*32;
  int tx = threadIdx.x, ty = threadIdx.y; // block (32,8)
  #pragma unroll
  for (int i=0;i<4;i++) tile[ty+8*i][tx] = in[(size_t)(r0+ty+8*i)*C + c0+tx];
  __syncthreads();
  #pragma unroll
  for (int i=0;i<4;i++) out[(size_t)(c0+ty+8*i)*R + r0+tx] = f2bf(tile[tx][ty+8*i]);
}

// ---------------- GEMM: C[M][N] = A[M][K](bf16) * Bt[N][K](bf16) + bias[N] ----------------
template<int OUT_BF16>
__global__ __launch_bounds__(256) void gemm_bt(const u16* __restrict__ A,
                                               const u16* __restrict__ Bt,
                                               const float* __restrict__ bias,
                                               void* __restrict__ Cp,
                                               int M, int N, int K){
  __shared__ __align__(16) u16 As[128*32];
  __shared__ __align__(16) u16 Bs[128*32];
  int tid = threadIdx.x, lane = tid&63, wv = tid>>6;
  int wr = wv>>1, wc = wv&1;
  int lr16 = lane&15, lg = lane>>4;
  size_t brow = (size_t)blockIdx.y*128, bcol = (size_t)blockIdx.x*128;
  f32x4 acc[4][4] = {};
  int nk = K>>5;
  for (int kt=0; kt<nk; ++kt){
    int k0 = kt*32;
    #pragma unroll
    for (int c=0;c<2;c++){
      gld_lds16(A  + (brow + c*64 + (tid>>2))*K + k0 + (tid&3)*8, &As[c*2048 + tid*8]);
      gld_lds16(Bt + (bcol + c*64 + (tid>>2))*K + k0 + (tid&3)*8, &Bs[c*2048 + tid*8]);
    }
    __syncthreads();
    short8 af[4], bfr[4];
    #pragma unroll
    for (int m=0;m<4;m++) af[m]  = *(const short8*)&As[(wr*64 + m*16 + lr16)*32 + lg*8];
    #pragma unroll
    for (int n=0;n<4;n++) bfr[n] = *(const short8*)&Bs[(wc*64 + n*16 + lr16)*32 + lg*8];
    #pragma unroll
    for (int m=0;m<4;m++)
      #pragma unroll
      for (int n=0;n<4;n++) acc[m][n] = MFMA(af[m], bfr[n], acc[m][n]);
    __syncthreads();
  }
  #pragma unroll
  for (int n=0;n<4;n++){
    size_t col = bcol + wc*64 + n*16 + lr16;
    float bs = bias[col];
    #pragma unroll
    for (int m=0;m<4;m++)
      #pragma unroll
      for (int j=0;j<4;j++){
        size_t row = brow + wr*64 + m*16 + lg*4 + j;
        float v = acc[m][n][j] + bs;
        if (OUT_BF16) ((u16*)Cp)[row*(size_t)N + col] = f2bf(v);
        else          ((float*)Cp)[row*(size_t)N + col] = v;
      }
  }
}

// ---------------- flash attention, causal, hs=64, H=16 ----------------
// Block: 4 waves, QBLK=128 (32 q/wave as 2x16), KVBLK=64.
// Swapped QK^T (lane holds one q-row slice of S^T). All LDS tiles XOR-swizzled:
//   Ks: chunk ^= row&7           (staged via global_load_lds, pre-swizzled source)
//   Vt[d][kv]: chunk ^= (d&7)^((d>>3)&7)  (reg-scatter write + b128 read both 2-way)
//   Pl[q][kv]: chunk ^= q&7
__global__ __launch_bounds__(256) void k_attn(const u16* __restrict__ qkv,
                                              u16* __restrict__ o, int T){
  __shared__ __align__(16) u16 Ks[64*64];
  __shared__ __align__(16) u16 Vt[64*64];
  __shared__ __align__(16) u16 Pl[4][32*64];
  int tid = threadIdx.x, lane = tid&63, wv = tid>>6;
  int qt = blockIdx.x, bh = blockIdx.y;
  int b = bh>>4, h = bh&15;
  size_t bt0 = (size_t)b*T;
  int qbase = qt*128;
  int lr16 = lane&15, lg = lane>>4;

  // Q fragments (B-operand of swapped QK^T), 2 q-groups; 0.125 scale exact (pow2)
  short8 qf[2][2];
  #pragma unroll
  for (int g=0; g<2; ++g){
    const u16* qp = qkv + (bt0 + qbase + wv*32 + g*16 + lr16)*3072 + h*192 + lg*8;
    #pragma unroll
    for (int t=0;t<2;t++){
      u16x8 v = *(const u16x8*)(qp + t*32);
      #pragma unroll
      for (int j=0;j<8;j++) v[j] = f2bf(bf2f(v[j])*0.125f);
      qf[g][t] = __builtin_bit_cast(short8, v);
    }
  }
  f32x4 O[2][4] = {};
  float m_run[2] = {-1e30f,-1e30f}, l_run[2] = {0.f,0.f};
  int qglob[2] = {qbase + wv*32 + lr16, qbase + wv*32 + 16 + lr16};
  int nkv = 2*qt + 2;
  for (int kb=0; kb<nkv; ++kb){
    int kv0 = kb*64;
    // ---- stage K (gld_lds, source pre-swizzled so linear LDS = swizzled layout)
    #pragma unroll
    for (int p=0; p<2; ++p){
      int oe = p*2048 + tid*8;
      int row = oe>>6;
      int cs = ((tid&7) ^ (row&7))*8;
      gld_lds16(qkv + (bt0+kv0+row)*3072 + h*192 + 64 + cs, &Ks[oe]);
    }
    // ---- stage V transposed: Vt[d][kv], double-XOR swizzle
    #pragma unroll
    for (int p=0; p<2; ++p){
      int r = p*32 + (tid>>3), c8 = (tid&7)*8;
      u16x8 vv = *(const u16x8*)(qkv + (bt0+kv0+r)*3072 + h*192 + 128 + c8);
      #pragma unroll
      for (int j=0;j<8;j++){
        int d = c8+j;
        int cp = (r>>3) ^ (d&7) ^ ((d>>3)&7);
        Vt[d*64 + cp*8 + (r&7)] = vv[j];
      }
    }
    __syncthreads();
    // ---- QK^T: st[g][s], s = kv 16-block
    f32x4 st[2][4];
    #pragma unroll
    for (int s=0;s<4;s++){
      int row = s*16 + lr16;
      int rx = row&7;
      short8 kf0 = *(const short8*)&Ks[row*64 + ((lg  )^rx)*8];
      short8 kf1 = *(const short8*)&Ks[row*64 + ((4+lg)^rx)*8];
      #pragma unroll
      for (int g=0; g<2; ++g){
        f32x4 z = {0,0,0,0};
        z = MFMA(kf0, qf[g][0], z);
        z = MFMA(kf1, qf[g][1], z);
        st[g][s] = z;
      }
    }
    bool need_mask = (kb >= 2*qt);
    #pragma unroll
    for (int g=0; g<2; ++g){
      if (need_mask){
        #pragma unroll
        for (int s=0;s<4;s++)
          #pragma unroll
          for (int j=0;j<4;j++){
            int kvg = kv0 + s*16 + lg*4 + j;
            if (kvg > qglob[g]) st[g][s][j] = -1e30f;
          }
      }
      float mx = -1e30f;
      #pragma unroll
      for (int s=0;s<4;s++)
        #pragma unroll
        for (int j=0;j<4;j++) mx = fmaxf(mx, st[g][s][j]);
      mx = fmaxf(mx, __shfl_xor(mx, 16));
      mx = fmaxf(mx, __shfl_xor(mx, 32));
      float m_new = fmaxf(m_run[g], mx);
      float al = __expf(m_run[g] - m_new);
      float ps = 0.f;
      u32 pw[8];
      #pragma unroll
      for (int s=0;s<4;s++){
        float p0 = __expf(st[g][s][0]-m_new), p1 = __expf(st[g][s][1]-m_new);
        float p2 = __expf(st[g][s][2]-m_new), p3 = __expf(st[g][s][3]-m_new);
        ps += (p0+p1)+(p2+p3);
        pw[s*2+0] = (u32)f2bf(p0) | ((u32)f2bf(p1)<<16);
        pw[s*2+1] = (u32)f2bf(p2) | ((u32)f2bf(p3)<<16);
      }
      ps += __shfl_xor(ps, 16);
      ps += __shfl_xor(ps, 32);
      l_run[g] = l_run[g]*al + ps;
      m_run[g] = m_new;
      // write P to swizzled Pl (per-wave; same-wave ordering via lgkmcnt)
      int q = g*16 + lr16, qx = lr16&7;
      #pragma unroll
      for (int s=0;s<4;s++){
        int cp = (s*2 + (lg>>1)) ^ qx;
        u32x2 w2; w2[0] = pw[s*2]; w2[1] = pw[s*2+1];
        *(u32x2*)&Pl[wv][q*64 + cp*8 + (lg&1)*4] = w2;
      }
      // rescale O rows (rows q=lg*4+j need alpha from lane q)
      float arow[4];
      #pragma unroll
      for (int j=0;j<4;j++) arow[j] = __shfl(al, lg*4 + j);
      #pragma unroll
      for (int db=0;db<4;db++)
        #pragma unroll
        for (int j=0;j<4;j++) O[g][db][j] *= arow[j];
    }
    // ---- PV: O[q][d] += P[q][kv] * V[kv][d], two kv32-blocks
    #pragma unroll
    for (int B=0;B<2;B++){
      short8 pa[2];
      #pragma unroll
      for (int g=0; g<2; ++g)
        pa[g] = *(const short8*)&Pl[wv][(g*16+lr16)*64 + (((B<<2)+lg)^(lr16&7))*8];
      #pragma unroll
      for (int db=0;db<4;db++){
        int d = db*16 + lr16;
        short8 vf = *(const short8*)&Vt[d*64 + ((((B<<2)+lg)^(d&7))^((d>>3)&7))*8];
        O[0][db] = MFMA(pa[0], vf, O[0][db]);
        O[1][db] = MFMA(pa[1], vf, O[1][db]);
      }
    }
    __syncthreads();
  }
  // writeout
  #pragma unroll
  for (int g=0; g<2; ++g){
    float lrow[4];
    #pragma unroll
    for (int j=0;j<4;j++) lrow[j] = __shfl(l_run[g], lg*4 + j);
    #pragma unroll
    for (int db=0;db<4;db++)
      #pragma unroll
      for (int j=0;j<4;j++){
        size_t row = bt0 + qbase + wv*32 + g*16 + lg*4 + j;
        o[row*1024 + h*64 + db*16 + lr16] = f2bf(O[g][db][j] / lrow[j]);
      }
  }
}

extern "C" void kernel_launch(void* const* d_in, const int* in_sizes, int n_in,
                              void* d_out, int out_size, void* d_ws, size_t ws_size,
                              hipStream_t stream){
  (void)in_sizes; (void)n_in; (void)out_size; (void)ws_size;
  const float* x     = (const float*)d_in[0];
  const float* Wqkv  = (const float*)d_in[1];
  const float* bqkv  = (const float*)d_in[2];
  const float* Wproj = (const float*)d_in[3];
  const float* bproj = (const float*)d_in[4];
  float* out = (float*)d_out;
  const int B=4, T=2048, C=1024;
  const int M = B*T; // 8192
  char* ws = (char*)d_ws;
  u16* qkvb   = (u16*)(ws);                 // 8192*3072 bf16 = 50331648 B
  u16* attnb  = (u16*)(ws + 50331648);      // 8192*1024 bf16 = 16777216 B
  u16* xb     = (u16*)(ws + 67108864);      // 8192*1024 bf16 = 16777216 B
  u16* wqkvT  = (u16*)(ws + 83886080);      // 3072*1024 bf16 =  6291456 B
  u16* wprojT = (u16*)(ws + 90177536);      // 1024*1024 bf16 =  2097152 B

  k_cast_x<<<4096, 256, 0, stream>>>(x, xb, M*C/8);
  dim3 tb(32,8);
  k_transpose_cast<<<dim3(96,32), tb, 0, stream>>>(Wqkv, wqkvT, C, 3*C);
  k_transpose_cast<<<dim3(32,32), tb, 0, stream>>>(Wproj, wprojT, C, C);
  gemm_bt<1><<<dim3(24,64), 256, 0, stream>>>(xb, wqkvT, bqkv, qkvb, M, 3*C, C);
  k_attn<<<dim3(16,64), 256, 0, stream>>>(qkvb, attnb, T);
  gemm_bt<0><<<dim3(8,64), 256, 0, stream>>>(attnb, wprojT, bproj, out, M, C, C);
}

// Round 5
// 228.803 us; speedup vs baseline: 2.0909x; 1.3404x over previous
//
#include <hip/hip_runtime.h>

typedef unsigned short u16;
typedef unsigned int u32;
typedef __attribute__((ext_vector_type(8))) short short8;
typedef __attribute__((ext_vector_type(8))) unsigned short u16x8;
typedef __attribute__((ext_vector_type(4))) unsigned short u16x4;
typedef __attribute__((ext_vector_type(2))) unsigned int u32x2;
typedef __attribute__((ext_vector_type(4))) float f32x4;

__device__ __forceinline__ u16 f2bf(float f){
  u32 u = __builtin_bit_cast(u32, f);
  u32 r = u + 0x7FFFu + ((u >> 16) & 1u);
  return (u16)(r >> 16);
}
__device__ __forceinline__ float bf2f(u16 h){
  u32 u = ((u32)h) << 16;
  return __builtin_bit_cast(float, u);
}

__device__ __forceinline__ void gld_lds16(const u16* g, u16* l){
  __builtin_amdgcn_global_load_lds(
      (const __attribute__((address_space(1))) u32*)g,
      (__attribute__((address_space(3))) u32*)l, 16, 0, 0);
}

#define MFMA(a,b,c) __builtin_amdgcn_mfma_f32_16x16x32_bf16((a),(b),(c),0,0,0)

// ---------------- cast x (f32 -> bf16), 8 elems/thread ----------------
__global__ void k_cast_x(const float* __restrict__ in, u16* __restrict__ out, int n8){
  int i = blockIdx.x*256 + threadIdx.x;
  if (i >= n8) return;
  const float4 a = ((const float4*)in)[2*i];
  const float4 b = ((const float4*)in)[2*i+1];
  u16x8 o;
  o[0]=f2bf(a.x); o[1]=f2bf(a.y); o[2]=f2bf(a.z); o[3]=f2bf(a.w);
  o[4]=f2bf(b.x); o[5]=f2bf(b.y); o[6]=f2bf(b.z); o[7]=f2bf(b.w);
  ((u16x8*)out)[i] = o;
}

// ---------------- transpose + cast: in[R][C] f32 -> out[C][R] bf16 ----------------
__global__ void k_transpose_cast(const float* __restrict__ in, u16* __restrict__ out,
                                 int R, int C){
  __shared__ float tile[32][33];
  int c0 = blockIdx.x*32, r0 = blockIdx.y*32;
  int tx = threadIdx.x, ty = threadIdx.y; // block (32,8)
  #pragma unroll
  for (int i=0;i<4;i++) tile[ty+8*i][tx] = in[(size_t)(r0+ty+8*i)*C + c0+tx];
  __syncthreads();
  #pragma unroll
  for (int i=0;i<4;i++) out[(size_t)(c0+ty+8*i)*R + r0+tx] = f2bf(tile[tx][ty+8*i]);
}

// ---------------- GEMM: C[M][N] = A[M][K](bf16) * Bt[N][K](bf16) + bias[N] ----------------
template<int OUT_BF16>
__global__ __launch_bounds__(256) void gemm_bt(const u16* __restrict__ A,
                                               const u16* __restrict__ Bt,
                                               const float* __restrict__ bias,
                                               void* __restrict__ Cp,
                                               int M, int N, int K){
  __shared__ __align__(16) u16 As[128*32];
  __shared__ __align__(16) u16 Bs[128*32];
  int tid = threadIdx.x, lane = tid&63, wv = tid>>6;
  int wr = wv>>1, wc = wv&1;
  int lr16 = lane&15, lg = lane>>4;
  size_t brow = (size_t)blockIdx.y*128, bcol = (size_t)blockIdx.x*128;
  f32x4 acc[4][4] = {};
  int nk = K>>5;
  for (int kt=0; kt<nk; ++kt){
    int k0 = kt*32;
    #pragma unroll
    for (int c=0;c<2;c++){
      gld_lds16(A  + (brow + c*64 + (tid>>2))*K + k0 + (tid&3)*8, &As[c*2048 + tid*8]);
      gld_lds16(Bt + (bcol + c*64 + (tid>>2))*K + k0 + (tid&3)*8, &Bs[c*2048 + tid*8]);
    }
    __syncthreads();
    short8 af[4], bfr[4];
    #pragma unroll
    for (int m=0;m<4;m++) af[m]  = *(const short8*)&As[(wr*64 + m*16 + lr16)*32 + lg*8];
    #pragma unroll
    for (int n=0;n<4;n++) bfr[n] = *(const short8*)&Bs[(wc*64 + n*16 + lr16)*32 + lg*8];
    #pragma unroll
    for (int m=0;m<4;m++)
      #pragma unroll
      for (int n=0;n<4;n++) acc[m][n] = MFMA(af[m], bfr[n], acc[m][n]);
    __syncthreads();
  }
  #pragma unroll
  for (int n=0;n<4;n++){
    size_t col = bcol + wc*64 + n*16 + lr16;
    float bs = bias[col];
    #pragma unroll
    for (int m=0;m<4;m++)
      #pragma unroll
      for (int j=0;j<4;j++){
        size_t row = brow + wr*64 + m*16 + lg*4 + j;
        float v = acc[m][n][j] + bs;
        if (OUT_BF16) ((u16*)Cp)[row*(size_t)N + col] = f2bf(v);
        else          ((float*)Cp)[row*(size_t)N + col] = v;
      }
  }
}

// ---------------- flash attention, causal, hs=64, H=16 ----------------
// 4 waves, QBLK=128 (32 q/wave as 2x16), KVBLK=64. Double-buffered K/V with
// async-stage split (loads issued before compute, V written after softmax).
// Longest-first dispatch: qt = 15 - blockIdx.y. Swizzles:
//   Ks: chunk ^= row&7  (gld_lds, pre-swizzled global source)
//   Vt[d][kv]: chunk ^= (d&7)^((d>>3)&7)  (register-pair transpose, b64 writes)
//   Pl[q][kv]: chunk ^= q&7
__global__ __launch_bounds__(256) void k_attn(const u16* __restrict__ qkv,
                                              u16* __restrict__ o, int T){
  __shared__ __align__(16) u16 Ks[2][64*64];
  __shared__ __align__(16) u16 Vt[2][64*64];
  __shared__ __align__(16) u16 Pl[4][32*64];
  int tid = threadIdx.x, lane = tid&63, wv = tid>>6;
  int bh = blockIdx.x;
  int qt = 15 - (int)blockIdx.y;          // longest-first
  int b = bh>>4, h = bh&15;
  size_t bt0 = (size_t)b*T;
  int qbase = qt*128;
  int lr16 = lane&15, lg = lane>>4;

  // staging geometry
  int vr0 = (tid>>4)*4, vd0 = (tid&15)*4;             // V: 4 rows x 4 d per thread
  int kr  = tid>>3;                                    // K: row within 32-half
  int kcs = ((tid&7) ^ (kr&7))*8;                      // pre-swizzled source col
  u16x4 va[4];

  // Q fragments (B-operand of swapped QK^T); 0.125 scale exact (pow2)
  short8 qf[2][2];
  #pragma unroll
  for (int g=0; g<2; ++g){
    const u16* qp = qkv + (bt0 + qbase + wv*32 + g*16 + lr16)*3072 + h*192 + lg*8;
    #pragma unroll
    for (int t=0;t<2;t++){
      u16x8 v = *(const u16x8*)(qp + t*32);
      #pragma unroll
      for (int j=0;j<8;j++) v[j] = f2bf(bf2f(v[j])*0.125f);
      qf[g][t] = __builtin_bit_cast(short8, v);
    }
  }
  f32x4 O[2][4] = {};
  float m_run[2] = {-1e30f,-1e30f}, l_run[2] = {0.f,0.f};
  int qglob[2] = {qbase + wv*32 + lr16, qbase + wv*32 + 16 + lr16};

  // prologue: stage tile 0 into buffer 0
  {
    #pragma unroll
    for (int i=0;i<4;i++)
      va[i] = *(const u16x4*)(qkv + (bt0 + vr0 + i)*3072 + h*192 + 128 + vd0);
    #pragma unroll
    for (int p=0;p<2;p++){
      int row = p*32 + kr;
      gld_lds16(qkv + (bt0+row)*3072 + h*192 + 64 + kcs, &Ks[0][p*2048 + tid*8]);
    }
    #pragma unroll
    for (int k=0;k<4;k++){
      int d = vd0+k;
      int c = (vr0>>3) ^ (d&7) ^ ((d>>3)&7);
      u32x2 w;
      w[0] = (u32)va[0][k] | ((u32)va[1][k]<<16);
      w[1] = (u32)va[2][k] | ((u32)va[3][k]<<16);
      *(u32x2*)&Vt[0][d*64 + c*8 + (vr0&7)] = w;
    }
  }
  __syncthreads();

  int nkv = 2*qt + 2;
  for (int kb=0; kb<nkv; ++kb){
    int cur = kb&1;
    int kv0 = kb*64;
    bool pf = (kb+1 < nkv);
    // ---- issue prefetch for tile kb+1 (V loads first, then K glds)
    if (pf){
      int kv1 = kv0 + 64;
      #pragma unroll
      for (int i=0;i<4;i++)
        va[i] = *(const u16x4*)(qkv + (bt0 + kv1 + vr0 + i)*3072 + h*192 + 128 + vd0);
      #pragma unroll
      for (int p=0;p<2;p++){
        int row = p*32 + kr;
        gld_lds16(qkv + (bt0+kv1+row)*3072 + h*192 + 64 + kcs, &Ks[cur^1][p*2048 + tid*8]);
      }
    }
    // ---- QK^T from Ks[cur]
    f32x4 st[2][4];
    __builtin_amdgcn_s_setprio(1);
    #pragma unroll
    for (int s=0;s<4;s++){
      int row = s*16 + lr16;
      int rx = row&7;
      short8 kf0 = *(const short8*)&Ks[cur][row*64 + ((lg  )^rx)*8];
      short8 kf1 = *(const short8*)&Ks[cur][row*64 + ((4+lg)^rx)*8];
      #pragma unroll
      for (int g=0; g<2; ++g){
        f32x4 z = {0,0,0,0};
        z = MFMA(kf0, qf[g][0], z);
        z = MFMA(kf1, qf[g][1], z);
        st[g][s] = z;
      }
    }
    __builtin_amdgcn_s_setprio(0);
    // ---- softmax (per q-group)
    bool need_mask = (kb >= 2*qt);
    #pragma unroll
    for (int g=0; g<2; ++g){
      if (need_mask){
        #pragma unroll
        for (int s=0;s<4;s++)
          #pragma unroll
          for (int j=0;j<4;j++){
            int kvg = kv0 + s*16 + lg*4 + j;
            if (kvg > qglob[g]) st[g][s][j] = -1e30f;
          }
      }
      float mx = -1e30f;
      #pragma unroll
      for (int s=0;s<4;s++)
        #pragma unroll
        for (int j=0;j<4;j++) mx = fmaxf(mx, st[g][s][j]);
      mx = fmaxf(mx, __shfl_xor(mx, 16));
      mx = fmaxf(mx, __shfl_xor(mx, 32));
      float m_new = fmaxf(m_run[g], mx);
      float al = __expf(m_run[g] - m_new);
      float ps = 0.f;
      u32 pw[8];
      #pragma unroll
      for (int s=0;s<4;s++){
        float p0 = __expf(st[g][s][0]-m_new), p1 = __expf(st[g][s][1]-m_new);
        float p2 = __expf(st[g][s][2]-m_new), p3 = __expf(st[g][s][3]-m_new);
        ps += (p0+p1)+(p2+p3);
        pw[s*2+0] = (u32)f2bf(p0) | ((u32)f2bf(p1)<<16);
        pw[s*2+1] = (u32)f2bf(p2) | ((u32)f2bf(p3)<<16);
      }
      ps += __shfl_xor(ps, 16);
      ps += __shfl_xor(ps, 32);
      l_run[g] = l_run[g]*al + ps;
      m_run[g] = m_new;
      int q = g*16 + lr16, qx = lr16&7;
      #pragma unroll
      for (int s=0;s<4;s++){
        int cp = (s*2 + (lg>>1)) ^ qx;
        u32x2 w2; w2[0] = pw[s*2]; w2[1] = pw[s*2+1];
        *(u32x2*)&Pl[wv][q*64 + cp*8 + (lg&1)*4] = w2;
      }
      float arow[4];
      #pragma unroll
      for (int j=0;j<4;j++) arow[j] = __shfl(al, lg*4 + j);
      #pragma unroll
      for (int db=0;db<4;db++)
        #pragma unroll
        for (int j=0;j<4;j++) O[g][db][j] *= arow[j];
    }
    // ---- write prefetched V into Vt[cur^1] (vmcnt wait auto-inserted for va)
    if (pf){
      #pragma unroll
      for (int k=0;k<4;k++){
        int d = vd0+k;
        int c = (vr0>>3) ^ (d&7) ^ ((d>>3)&7);
        u32x2 w;
        w[0] = (u32)va[0][k] | ((u32)va[1][k]<<16);
        w[1] = (u32)va[2][k] | ((u32)va[3][k]<<16);
        *(u32x2*)&Vt[cur^1][d*64 + c*8 + (vr0&7)] = w;
      }
    }
    // ---- PV from Vt[cur], Pl
    __builtin_amdgcn_s_setprio(1);
    #pragma unroll
    for (int B=0;B<2;B++){
      short8 pa[2];
      #pragma unroll
      for (int g=0; g<2; ++g)
        pa[g] = *(const short8*)&Pl[wv][(g*16+lr16)*64 + (((B<<2)+lg)^(lr16&7))*8];
      #pragma unroll
      for (int db=0;db<4;db++){
        int d = db*16 + lr16;
        short8 vf = *(const short8*)&Vt[cur][d*64 + ((((B<<2)+lg)^(d&7))^((d>>3)&7))*8];
        O[0][db] = MFMA(pa[0], vf, O[0][db]);
        O[1][db] = MFMA(pa[1], vf, O[1][db]);
      }
    }
    __builtin_amdgcn_s_setprio(0);
    __syncthreads();
  }
  // writeout
  #pragma unroll
  for (int g=0; g<2; ++g){
    float lrow[4];
    #pragma unroll
    for (int j=0;j<4;j++) lrow[j] = __shfl(l_run[g], lg*4 + j);
    #pragma unroll
    for (int db=0;db<4;db++)
      #pragma unroll
      for (int j=0;j<4;j++){
        size_t row = bt0 + qbase + wv*32 + g*16 + lg*4 + j;
        o[row*1024 + h*64 + db*16 + lr16] = f2bf(O[g][db][j] / lrow[j]);
      }
  }
}

extern "C" void kernel_launch(void* const* d_in, const int* in_sizes, int n_in,
                              void* d_out, int out_size, void* d_ws, size_t ws_size,
                              hipStream_t stream){
  (void)in_sizes; (void)n_in; (void)out_size; (void)ws_size;
  const float* x     = (const float*)d_in[0];
  const float* Wqkv  = (const float*)d_in[1];
  const float* bqkv  = (const float*)d_in[2];
  const float* Wproj = (const float*)d_in[3];
  const float* bproj = (const float*)d_in[4];
  float* out = (float*)d_out;
  const int B=4, T=2048, C=1024;
  const int M = B*T; // 8192
  char* ws = (char*)d_ws;
  u16* qkvb   = (u16*)(ws);                 // 8192*3072 bf16 = 50331648 B
  u16* attnb  = (u16*)(ws + 50331648);      // 8192*1024 bf16 = 16777216 B
  u16* xb     = (u16*)(ws + 67108864);      // 8192*1024 bf16 = 16777216 B
  u16* wqkvT  = (u16*)(ws + 83886080);      // 3072*1024 bf16 =  6291456 B
  u16* wprojT = (u16*)(ws + 90177536);      // 1024*1024 bf16 =  2097152 B

  k_cast_x<<<4096, 256, 0, stream>>>(x, xb, M*C/8);
  dim3 tb(32,8);
  k_transpose_cast<<<dim3(96,32), tb, 0, stream>>>(Wqkv, wqkvT, C, 3*C);
  k_transpose_cast<<<dim3(32,32), tb, 0, stream>>>(Wproj, wprojT, C, C);
  gemm_bt<1><<<dim3(24,64), 256, 0, stream>>>(xb, wqkvT, bqkv, qkvb, M, 3*C, C);
  k_attn<<<dim3(64,16), 256, 0, stream>>>(qkvb, attnb, T);
  gemm_bt<0><<<dim3(8,64), 256, 0, stream>>>(attnb, wprojT, bproj, out, M, C, C);
}

// Round 6
// 226.088 us; speedup vs baseline: 2.1160x; 1.0120x over previous
//
#include <hip/hip_runtime.h>

typedef unsigned short u16;
typedef unsigned int u32;
typedef __attribute__((ext_vector_type(8))) short short8;
typedef __attribute__((ext_vector_type(8))) unsigned short u16x8;
typedef __attribute__((ext_vector_type(4))) unsigned short u16x4;
typedef __attribute__((ext_vector_type(2))) unsigned int u32x2;
typedef __attribute__((ext_vector_type(4))) float f32x4;

__device__ __forceinline__ u16 f2bf(float f){
  u32 u = __builtin_bit_cast(u32, f);
  u32 r = u + 0x7FFFu + ((u >> 16) & 1u);
  return (u16)(r >> 16);
}
__device__ __forceinline__ float bf2f(u16 h){
  u32 u = ((u32)h) << 16;
  return __builtin_bit_cast(float, u);
}
__device__ __forceinline__ float f3max(float a, float b, float c){
  return fmaxf(a, fmaxf(b, c));   // fuses to v_max3_f32
}
__device__ __forceinline__ u32 cvtpk(float lo, float hi){
  u32 r;
  asm("v_cvt_pk_bf16_f32 %0, %1, %2" : "=v"(r) : "v"(lo), "v"(hi));
  return r;
}

__device__ __forceinline__ void gld_lds16(const u16* g, u16* l){
  __builtin_amdgcn_global_load_lds(
      (const __attribute__((address_space(1))) u32*)g,
      (__attribute__((address_space(3))) u32*)l, 16, 0, 0);
}

#define MFMA(a,b,c) __builtin_amdgcn_mfma_f32_16x16x32_bf16((a),(b),(c),0,0,0)

// ---------------- cast x (f32 -> bf16), 8 elems/thread ----------------
__global__ void k_cast_x(const float* __restrict__ in, u16* __restrict__ out, int n8){
  int i = blockIdx.x*256 + threadIdx.x;
  if (i >= n8) return;
  const float4 a = ((const float4*)in)[2*i];
  const float4 b = ((const float4*)in)[2*i+1];
  u16x8 o;
  o[0]=f2bf(a.x); o[1]=f2bf(a.y); o[2]=f2bf(a.z); o[3]=f2bf(a.w);
  o[4]=f2bf(b.x); o[5]=f2bf(b.y); o[6]=f2bf(b.z); o[7]=f2bf(b.w);
  ((u16x8*)out)[i] = o;
}

// ---------------- transpose + cast: in[R][C] f32 -> out[C][R] bf16 ----------------
__global__ void k_transpose_cast(const float* __restrict__ in, u16* __restrict__ out,
                                 int R, int C){
  __shared__ float tile[32][33];
  int c0 = blockIdx.x*32, r0 = blockIdx.y*32;
  int tx = threadIdx.x, ty = threadIdx.y; // block (32,8)
  #pragma unroll
  for (int i=0;i<4;i++) tile[ty+8*i][tx] = in[(size_t)(r0+ty+8*i)*C + c0+tx];
  __syncthreads();
  #pragma unroll
  for (int i=0;i<4;i++) out[(size_t)(c0+ty+8*i)*R + r0+tx] = f2bf(tile[tx][ty+8*i]);
}

// ---------------- GEMM: C[M][N] = A[M][K](bf16) * Bt[N][K](bf16) + bias[N] ----------------
// 128x128 tile, BK=32, 4 waves, m97 structure + XCD-aware block swizzle (T1).
template<int OUT_BF16>
__global__ __launch_bounds__(256) void gemm_bt(const u16* __restrict__ A,
                                               const u16* __restrict__ Bt,
                                               const float* __restrict__ bias,
                                               void* __restrict__ Cp,
                                               int M, int N, int K){
  __shared__ __align__(16) u16 As[128*32];
  __shared__ __align__(16) u16 Bs[128*32];
  int tid = threadIdx.x, lane = tid&63, wv = tid>>6;
  int wr = wv>>1, wc = wv&1;
  int lr16 = lane&15, lg = lane>>4;
  // XCD swizzle (grid size % 8 == 0 for both GEMMs)
  int nwg = gridDim.x*gridDim.y;
  int lin = blockIdx.y*gridDim.x + blockIdx.x;
  int cpx = nwg>>3;
  int swz = (lin&7)*cpx + (lin>>3);
  int bx = swz % gridDim.x, by = swz / gridDim.x;
  size_t brow = (size_t)by*128, bcol = (size_t)bx*128;
  f32x4 acc[4][4] = {};
  int nk = K>>5;
  for (int kt=0; kt<nk; ++kt){
    int k0 = kt*32;
    #pragma unroll
    for (int c=0;c<2;c++){
      gld_lds16(A  + (brow + c*64 + (tid>>2))*K + k0 + (tid&3)*8, &As[c*2048 + tid*8]);
      gld_lds16(Bt + (bcol + c*64 + (tid>>2))*K + k0 + (tid&3)*8, &Bs[c*2048 + tid*8]);
    }
    __syncthreads();
    short8 af[4], bfr[4];
    #pragma unroll
    for (int m=0;m<4;m++) af[m]  = *(const short8*)&As[(wr*64 + m*16 + lr16)*32 + lg*8];
    #pragma unroll
    for (int n=0;n<4;n++) bfr[n] = *(const short8*)&Bs[(wc*64 + n*16 + lr16)*32 + lg*8];
    #pragma unroll
    for (int m=0;m<4;m++)
      #pragma unroll
      for (int n=0;n<4;n++) acc[m][n] = MFMA(af[m], bfr[n], acc[m][n]);
    __syncthreads();
  }
  #pragma unroll
  for (int n=0;n<4;n++){
    size_t col = bcol + wc*64 + n*16 + lr16;
    float bs = bias[col];
    #pragma unroll
    for (int m=0;m<4;m++)
      #pragma unroll
      for (int j=0;j<4;j++){
        size_t row = brow + wr*64 + m*16 + lg*4 + j;
        float v = acc[m][n][j] + bs;
        if (OUT_BF16) ((u16*)Cp)[row*(size_t)N + col] = f2bf(v);
        else          ((float*)Cp)[row*(size_t)N + col] = v;
      }
  }
}

// ---------------- flash attention, causal, hs=64, H=16 ----------------
// 4 waves, QBLK=128 (32 q/wave as 2x16), KVBLK=64. Double-buffered K/V, async
// stage split, longest-first dispatch. Softmax in exp2 domain (scale*log2e
// folded into Q), defer-max THR=8, cvt_pk_bf16 P packing, max3 reduce.
__global__ __launch_bounds__(256) void k_attn(const u16* __restrict__ qkv,
                                              u16* __restrict__ o, int T){
  __shared__ __align__(16) u16 Ks[2][64*64];
  __shared__ __align__(16) u16 Vt[2][64*64];
  __shared__ __align__(16) u16 Pl[4][32*64];
  int tid = threadIdx.x, lane = tid&63, wv = tid>>6;
  int bh = blockIdx.x;
  int qt = 15 - (int)blockIdx.y;          // longest-first
  int b = bh>>4, h = bh&15;
  size_t bt0 = (size_t)b*T;
  int qbase = qt*128;
  int lr16 = lane&15, lg = lane>>4;

  // staging geometry
  int vr0 = (tid>>4)*4, vd0 = (tid&15)*4;             // V: 4 rows x 4 d per thread
  int kr  = tid>>3;                                    // K: row within 32-half
  int kcs = ((tid&7) ^ (kr&7))*8;                      // pre-swizzled source col
  u16x4 va[4];

  // Q fragments (B-operand of swapped QK^T); scale = 0.125*log2(e) (exp2 domain)
  const float QS = 0.18033688f;
  short8 qf[2][2];
  #pragma unroll
  for (int g=0; g<2; ++g){
    const u16* qp = qkv + (bt0 + qbase + wv*32 + g*16 + lr16)*3072 + h*192 + lg*8;
    #pragma unroll
    for (int t=0;t<2;t++){
      u16x8 v = *(const u16x8*)(qp + t*32);
      #pragma unroll
      for (int j=0;j<8;j++) v[j] = f2bf(bf2f(v[j])*QS);
      qf[g][t] = __builtin_bit_cast(short8, v);
    }
  }
  f32x4 O[2][4] = {};
  float m_run[2] = {-1e30f,-1e30f}, l_run[2] = {0.f,0.f};
  int qglob[2] = {qbase + wv*32 + lr16, qbase + wv*32 + 16 + lr16};

  // prologue: stage tile 0 into buffer 0
  {
    #pragma unroll
    for (int i=0;i<4;i++)
      va[i] = *(const u16x4*)(qkv + (bt0 + vr0 + i)*3072 + h*192 + 128 + vd0);
    #pragma unroll
    for (int p=0;p<2;p++){
      int row = p*32 + kr;
      gld_lds16(qkv + (bt0+row)*3072 + h*192 + 64 + kcs, &Ks[0][p*2048 + tid*8]);
    }
    #pragma unroll
    for (int k=0;k<4;k++){
      int d = vd0+k;
      int c = (vr0>>3) ^ (d&7) ^ ((d>>3)&7);
      u32x2 w;
      w[0] = (u32)va[0][k] | ((u32)va[1][k]<<16);
      w[1] = (u32)va[2][k] | ((u32)va[3][k]<<16);
      *(u32x2*)&Vt[0][d*64 + c*8 + (vr0&7)] = w;
    }
  }
  __syncthreads();

  int nkv = 2*qt + 2;
  for (int kb=0; kb<nkv; ++kb){
    int cur = kb&1;
    int kv0 = kb*64;
    bool pf = (kb+1 < nkv);
    // ---- issue prefetch for tile kb+1 (V loads first, then K glds)
    if (pf){
      int kv1 = kv0 + 64;
      #pragma unroll
      for (int i=0;i<4;i++)
        va[i] = *(const u16x4*)(qkv + (bt0 + kv1 + vr0 + i)*3072 + h*192 + 128 + vd0);
      #pragma unroll
      for (int p=0;p<2;p++){
        int row = p*32 + kr;
        gld_lds16(qkv + (bt0+kv1+row)*3072 + h*192 + 64 + kcs, &Ks[cur^1][p*2048 + tid*8]);
      }
    }
    // ---- QK^T from Ks[cur]
    f32x4 st[2][4];
    __builtin_amdgcn_s_setprio(1);
    #pragma unroll
    for (int s=0;s<4;s++){
      int row = s*16 + lr16;
      int rx = row&7;
      short8 kf0 = *(const short8*)&Ks[cur][row*64 + ((lg  )^rx)*8];
      short8 kf1 = *(const short8*)&Ks[cur][row*64 + ((4+lg)^rx)*8];
      #pragma unroll
      for (int g=0; g<2; ++g){
        f32x4 z = {0,0,0,0};
        z = MFMA(kf0, qf[g][0], z);
        z = MFMA(kf1, qf[g][1], z);
        st[g][s] = z;
      }
    }
    __builtin_amdgcn_s_setprio(0);
    // ---- softmax (per q-group), exp2 domain
    bool need_mask = (kb >= 2*qt);
    #pragma unroll
    for (int g=0; g<2; ++g){
      if (need_mask){
        #pragma unroll
        for (int s=0;s<4;s++)
          #pragma unroll
          for (int j=0;j<4;j++){
            int kvg = kv0 + s*16 + lg*4 + j;
            if (kvg > qglob[g]) st[g][s][j] = -1e30f;
          }
      }
      float mx = f3max(st[g][0][0], st[g][0][1], st[g][0][2]);
      mx = f3max(mx, st[g][0][3], st[g][1][0]);
      mx = f3max(mx, st[g][1][1], st[g][1][2]);
      mx = f3max(mx, st[g][1][3], st[g][2][0]);
      mx = f3max(mx, st[g][2][1], st[g][2][2]);
      mx = f3max(mx, st[g][2][3], st[g][3][0]);
      mx = f3max(mx, st[g][3][1], st[g][3][2]);
      mx = fmaxf(mx, st[g][3][3]);
      mx = fmaxf(mx, __shfl_xor(mx, 16));
      mx = fmaxf(mx, __shfl_xor(mx, 32));
      // defer-max: only rescale when the tile max grew past THR=8 (log2 units)
      if (__any(mx > m_run[g] + 8.f)){
        float m_new = fmaxf(m_run[g], mx);
        float al = exp2f(m_run[g] - m_new);
        m_run[g] = m_new;
        l_run[g] *= al;
        float arow[4];
        #pragma unroll
        for (int j=0;j<4;j++) arow[j] = __shfl(al, lg*4 + j);
        #pragma unroll
        for (int db=0;db<4;db++)
          #pragma unroll
          for (int j=0;j<4;j++) O[g][db][j] *= arow[j];
      }
      float mr = m_run[g];
      float ps = 0.f;
      u32 pw[8];
      #pragma unroll
      for (int s=0;s<4;s++){
        float p0 = exp2f(st[g][s][0]-mr), p1 = exp2f(st[g][s][1]-mr);
        float p2 = exp2f(st[g][s][2]-mr), p3 = exp2f(st[g][s][3]-mr);
        ps += (p0+p1)+(p2+p3);
        pw[s*2+0] = cvtpk(p0,p1);
        pw[s*2+1] = cvtpk(p2,p3);
      }
      ps += __shfl_xor(ps, 16);
      ps += __shfl_xor(ps, 32);
      l_run[g] += ps;
      int q = g*16 + lr16, qx = lr16&7;
      #pragma unroll
      for (int s=0;s<4;s++){
        int cp = (s*2 + (lg>>1)) ^ qx;
        u32x2 w2; w2[0] = pw[s*2]; w2[1] = pw[s*2+1];
        *(u32x2*)&Pl[wv][q*64 + cp*8 + (lg&1)*4] = w2;
      }
    }
    // ---- write prefetched V into Vt[cur^1]
    if (pf){
      #pragma unroll
      for (int k=0;k<4;k++){
        int d = vd0+k;
        int c = (vr0>>3) ^ (d&7) ^ ((d>>3)&7);
        u32x2 w;
        w[0] = (u32)va[0][k] | ((u32)va[1][k]<<16);
        w[1] = (u32)va[2][k] | ((u32)va[3][k]<<16);
        *(u32x2*)&Vt[cur^1][d*64 + c*8 + (vr0&7)] = w;
      }
    }
    // ---- PV from Vt[cur], Pl
    __builtin_amdgcn_s_setprio(1);
    #pragma unroll
    for (int B=0;B<2;B++){
      short8 pa[2];
      #pragma unroll
      for (int g=0; g<2; ++g)
        pa[g] = *(const short8*)&Pl[wv][(g*16+lr16)*64 + (((B<<2)+lg)^(lr16&7))*8];
      #pragma unroll
      for (int db=0;db<4;db++){
        int d = db*16 + lr16;
        short8 vf = *(const short8*)&Vt[cur][d*64 + ((((B<<2)+lg)^(d&7))^((d>>3)&7))*8];
        O[0][db] = MFMA(pa[0], vf, O[0][db]);
        O[1][db] = MFMA(pa[1], vf, O[1][db]);
      }
    }
    __builtin_amdgcn_s_setprio(0);
    __syncthreads();
  }
  // writeout (rcp instead of div)
  #pragma unroll
  for (int g=0; g<2; ++g){
    float lrow[4];
    #pragma unroll
    for (int j=0;j<4;j++) lrow[j] = __builtin_amdgcn_rcpf(__shfl(l_run[g], lg*4 + j));
    #pragma unroll
    for (int db=0;db<4;db++)
      #pragma unroll
      for (int j=0;j<4;j++){
        size_t row = bt0 + qbase + wv*32 + g*16 + lg*4 + j;
        o[row*1024 + h*64 + db*16 + lr16] = f2bf(O[g][db][j] * lrow[j]);
      }
  }
}

extern "C" void kernel_launch(void* const* d_in, const int* in_sizes, int n_in,
                              void* d_out, int out_size, void* d_ws, size_t ws_size,
                              hipStream_t stream){
  (void)in_sizes; (void)n_in; (void)out_size; (void)ws_size;
  const float* x     = (const float*)d_in[0];
  const float* Wqkv  = (const float*)d_in[1];
  const float* bqkv  = (const float*)d_in[2];
  const float* Wproj = (const float*)d_in[3];
  const float* bproj = (const float*)d_in[4];
  float* out = (float*)d_out;
  const int B=4, T=2048, C=1024;
  const int M = B*T; // 8192
  char* ws = (char*)d_ws;
  u16* qkvb   = (u16*)(ws);                 // 8192*3072 bf16 = 50331648 B
  u16* attnb  = (u16*)(ws + 50331648);      // 8192*1024 bf16 = 16777216 B
  u16* xb     = (u16*)(ws + 67108864);      // 8192*1024 bf16 = 16777216 B
  u16* wqkvT  = (u16*)(ws + 83886080);      // 3072*1024 bf16 =  6291456 B
  u16* wprojT = (u16*)(ws + 90177536);      // 1024*1024 bf16 =  2097152 B

  k_cast_x<<<4096, 256, 0, stream>>>(x, xb, M*C/8);
  dim3 tb(32,8);
  k_transpose_cast<<<dim3(96,32), tb, 0, stream>>>(Wqkv, wqkvT, C, 3*C);
  k_transpose_cast<<<dim3(32,32), tb, 0, stream>>>(Wproj, wprojT, C, C);
  gemm_bt<1><<<dim3(24,64), 256, 0, stream>>>(xb, wqkvT, bqkv, qkvb, M, 3*C, C);
  k_attn<<<dim3(64,16), 256, 0, stream>>>(qkvb, attnb, T);
  gemm_bt<0><<<dim3(8,64), 256, 0, stream>>>(attnb, wprojT, bproj, out, M, C, C);
}

// Round 8
// 223.790 us; speedup vs baseline: 2.1377x; 1.0103x over previous
//
#include <hip/hip_runtime.h>

typedef unsigned short u16;
typedef unsigned int u32;
typedef __attribute__((ext_vector_type(8))) short short8;
typedef __attribute__((ext_vector_type(8))) unsigned short u16x8;
typedef __attribute__((ext_vector_type(4))) unsigned short u16x4;
typedef __attribute__((ext_vector_type(2))) unsigned int u32x2;
typedef __attribute__((ext_vector_type(4))) float f32x4;

__device__ __forceinline__ u16 f2bf(float f){
  u32 u = __builtin_bit_cast(u32, f);
  u32 r = u + 0x7FFFu + ((u >> 16) & 1u);
  return (u16)(r >> 16);
}
__device__ __forceinline__ float bf2f(u16 h){
  u32 u = ((u32)h) << 16;
  return __builtin_bit_cast(float, u);
}
__device__ __forceinline__ float f3max(float a, float b, float c){
  return fmaxf(a, fmaxf(b, c));   // fuses to v_max3_f32
}
__device__ __forceinline__ u32 cvtpk(float lo, float hi){
  u32 r;
  asm("v_cvt_pk_bf16_f32 %0, %1, %2" : "=v"(r) : "v"(lo), "v"(hi));
  return r;
}

__device__ __forceinline__ void gld_lds16(const u16* g, u16* l){
  __builtin_amdgcn_global_load_lds(
      (const __attribute__((address_space(1))) u32*)g,
      (__attribute__((address_space(3))) u32*)l, 16, 0, 0);
}

#define MFMA(a,b,c) __builtin_amdgcn_mfma_f32_16x16x32_bf16((a),(b),(c),0,0,0)

// ---------------- cast x (f32 -> bf16), 8 elems/thread ----------------
__global__ void k_cast_x(const float* __restrict__ in, u16* __restrict__ out, int n8){
  int i = blockIdx.x*256 + threadIdx.x;
  if (i >= n8) return;
  const float4 a = ((const float4*)in)[2*i];
  const float4 b = ((const float4*)in)[2*i+1];
  u16x8 o;
  o[0]=f2bf(a.x); o[1]=f2bf(a.y); o[2]=f2bf(a.z); o[3]=f2bf(a.w);
  o[4]=f2bf(b.x); o[5]=f2bf(b.y); o[6]=f2bf(b.z); o[7]=f2bf(b.w);
  ((u16x8*)out)[i] = o;
}

// ---------------- transpose + cast: in[R][C] f32 -> out[C][R] bf16 ----------------
__global__ void k_transpose_cast(const float* __restrict__ in, u16* __restrict__ out,
                                 int R, int C){
  __shared__ float tile[32][33];
  int c0 = blockIdx.x*32, r0 = blockIdx.y*32;
  int tx = threadIdx.x, ty = threadIdx.y; // block (32,8)
  #pragma unroll
  for (int i=0;i<4;i++) tile[ty+8*i][tx] = in[(size_t)(r0+ty+8*i)*C + c0+tx];
  __syncthreads();
  #pragma unroll
  for (int i=0;i<4;i++) out[(size_t)(c0+ty+8*i)*R + r0+tx] = f2bf(tile[tx][ty+8*i]);
}

// ---------------- GEMM: C[M][N] = A[M][K](bf16) * Bt[N][K](bf16) + bias[N] ----------------
// 128x128 tile, BK=32, 4 waves, m97 structure + XCD-aware block swizzle (T1).
template<int OUT_BF16>
__global__ __launch_bounds__(256) void gemm_bt(const u16* __restrict__ A,
                                               const u16* __restrict__ Bt,
                                               const float* __restrict__ bias,
                                               void* __restrict__ Cp,
                                               int M, int N, int K){
  __shared__ __align__(16) u16 As[128*32];
  __shared__ __align__(16) u16 Bs[128*32];
  int tid = threadIdx.x, lane = tid&63, wv = tid>>6;
  int wr = wv>>1, wc = wv&1;
  int lr16 = lane&15, lg = lane>>4;
  // XCD swizzle (grid size % 8 == 0 for both GEMMs)
  int nwg = gridDim.x*gridDim.y;
  int lin = blockIdx.y*gridDim.x + blockIdx.x;
  int cpx = nwg>>3;
  int swz = (lin&7)*cpx + (lin>>3);
  int bx = swz % gridDim.x, by = swz / gridDim.x;
  size_t brow = (size_t)by*128, bcol = (size_t)bx*128;
  f32x4 acc[4][4] = {};
  int nk = K>>5;
  for (int kt=0; kt<nk; ++kt){
    int k0 = kt*32;
    #pragma unroll
    for (int c=0;c<2;c++){
      gld_lds16(A  + (brow + c*64 + (tid>>2))*K + k0 + (tid&3)*8, &As[c*2048 + tid*8]);
      gld_lds16(Bt + (bcol + c*64 + (tid>>2))*K + k0 + (tid&3)*8, &Bs[c*2048 + tid*8]);
    }
    __syncthreads();
    short8 af[4], bfr[4];
    #pragma unroll
    for (int m=0;m<4;m++) af[m]  = *(const short8*)&As[(wr*64 + m*16 + lr16)*32 + lg*8];
    #pragma unroll
    for (int n=0;n<4;n++) bfr[n] = *(const short8*)&Bs[(wc*64 + n*16 + lr16)*32 + lg*8];
    #pragma unroll
    for (int m=0;m<4;m++)
      #pragma unroll
      for (int n=0;n<4;n++) acc[m][n] = MFMA(af[m], bfr[n], acc[m][n]);
    __syncthreads();
  }
  #pragma unroll
  for (int n=0;n<4;n++){
    size_t col = bcol + wc*64 + n*16 + lr16;
    float bs = bias[col];
    #pragma unroll
    for (int m=0;m<4;m++)
      #pragma unroll
      for (int j=0;j<4;j++){
        size_t row = brow + wr*64 + m*16 + lg*4 + j;
        float v = acc[m][n][j] + bs;
        if (OUT_BF16) ((u16*)Cp)[row*(size_t)N + col] = f2bf(v);
        else          ((float*)Cp)[row*(size_t)N + col] = v;
      }
  }
}

// ---------------- flash attention, causal, hs=64, H=16 ----------------
// 4 waves, QBLK=128 (32 q/wave as 2x16), KVBLK=64. Each block processes TWO
// q-tiles (qt = 15-y then qt = y) -> every block does exactly 34 kv-iters
// (perfect balance, 512 equal blocks = 2/CU). kv-loop unrolled by 2 so the
// LDS double-buffer index is a literal (addresses loop-invariant).
// Swizzles: Ks chunk^=row&7 (pre-swizzled gld_lds source);
//           Vt[d][kv] chunk^=(d&7)^((d>>3)&7); Pl[q][kv] chunk^=q&7.
#define ATTN_ITER(KB, CUR, PF) do{                                             \
  int kv0 = (KB)*64;                                                           \
  if (PF){                                                                     \
    int kv1 = kv0 + 64;                                                        \
    _Pragma("unroll")                                                          \
    for (int i=0;i<4;i++)                                                      \
      va[i] = *(const u16x4*)(qkv + (bt0 + kv1 + vr0 + i)*3072 + hq + 128 + vd0); \
    _Pragma("unroll")                                                          \
    for (int p=0;p<2;p++){                                                     \
      int row = p*32 + kr;                                                     \
      gld_lds16(qkv + (bt0+kv1+row)*3072 + hq + 64 + kcs,                      \
                &Ks[(CUR)^1][p*2048 + tid*8]);                                 \
    }                                                                          \
  }                                                                            \
  f32x4 st[2][4];                                                              \
  __builtin_amdgcn_s_setprio(1);                                               \
  _Pragma("unroll")                                                            \
  for (int s=0;s<4;s++){                                                       \
    short8 kf0 = *(const short8*)&Ks[CUR][(s*16+lr16)*64 + ((lg  )^rx)*8];     \
    short8 kf1 = *(const short8*)&Ks[CUR][(s*16+lr16)*64 + ((4+lg)^rx)*8];     \
    _Pragma("unroll")                                                          \
    for (int g=0; g<2; ++g){                                                   \
      f32x4 z = {0,0,0,0};                                                     \
      z = MFMA(kf0, qf[g][0], z);                                              \
      z = MFMA(kf1, qf[g][1], z);                                              \
      st[g][s] = z;                                                            \
    }                                                                          \
  }                                                                            \
  __builtin_amdgcn_s_setprio(0);                                               \
  bool need_mask = (kv0 >= qbase);                                             \
  _Pragma("unroll")                                                            \
  for (int g=0; g<2; ++g){                                                     \
    if (need_mask){                                                            \
      _Pragma("unroll")                                                        \
      for (int s=0;s<4;s++)                                                    \
        _Pragma("unroll")                                                      \
        for (int j=0;j<4;j++){                                                 \
          int kvg = kv0 + s*16 + lg*4 + j;                                     \
          if (kvg > qglob[g]) st[g][s][j] = -1e30f;                            \
        }                                                                      \
    }                                                                          \
    float mx = f3max(st[g][0][0], st[g][0][1], st[g][0][2]);                   \
    mx = f3max(mx, st[g][0][3], st[g][1][0]);                                  \
    mx = f3max(mx, st[g][1][1], st[g][1][2]);                                  \
    mx = f3max(mx, st[g][1][3], st[g][2][0]);                                  \
    mx = f3max(mx, st[g][2][1], st[g][2][2]);                                  \
    mx = f3max(mx, st[g][2][3], st[g][3][0]);                                  \
    mx = f3max(mx, st[g][3][1], st[g][3][2]);                                  \
    mx = fmaxf(mx, st[g][3][3]);                                               \
    mx = fmaxf(mx, __shfl_xor(mx, 16));                                        \
    mx = fmaxf(mx, __shfl_xor(mx, 32));                                        \
    if (__any(mx > m_run[g] + 8.f)){                                           \
      float m_new = fmaxf(m_run[g], mx);                                       \
      float al = exp2f(m_run[g] - m_new);                                      \
      m_run[g] = m_new;                                                        \
      l_run[g] *= al;                                                          \
      float arow[4];                                                           \
      _Pragma("unroll")                                                        \
      for (int j=0;j<4;j++) arow[j] = __shfl(al, lg*4 + j);                    \
      _Pragma("unroll")                                                        \
      for (int db=0;db<4;db++)                                                 \
        _Pragma("unroll")                                                      \
        for (int j=0;j<4;j++) O[g][db][j] *= arow[j];                          \
    }                                                                          \
    float mr = m_run[g];                                                       \
    float ps = 0.f;                                                            \
    u32 pw[8];                                                                 \
    _Pragma("unroll")                                                          \
    for (int s=0;s<4;s++){                                                     \
      float p0 = exp2f(st[g][s][0]-mr), p1 = exp2f(st[g][s][1]-mr);            \
      float p2 = exp2f(st[g][s][2]-mr), p3 = exp2f(st[g][s][3]-mr);            \
      ps += (p0+p1)+(p2+p3);                                                   \
      pw[s*2+0] = cvtpk(p0,p1);                                                \
      pw[s*2+1] = cvtpk(p2,p3);                                                \
    }                                                                          \
    ps += __shfl_xor(ps, 16);                                                  \
    ps += __shfl_xor(ps, 32);                                                  \
    l_run[g] += ps;                                                            \
    int q = g*16 + lr16, qx = lr16&7;                                          \
    _Pragma("unroll")                                                          \
    for (int s=0;s<4;s++){                                                     \
      int cp = (s*2 + (lg>>1)) ^ qx;                                           \
      u32x2 w2; w2[0] = pw[s*2]; w2[1] = pw[s*2+1];                            \
      *(u32x2*)&Pl[wv][q*64 + cp*8 + (lg&1)*4] = w2;                           \
    }                                                                          \
  }                                                                            \
  if (PF){                                                                     \
    _Pragma("unroll")                                                          \
    for (int k=0;k<4;k++){                                                     \
      int d = vd0+k;                                                           \
      int c = (vr0>>3) ^ (d&7) ^ ((d>>3)&7);                                   \
      u32x2 w;                                                                 \
      w[0] = (u32)va[0][k] | ((u32)va[1][k]<<16);                              \
      w[1] = (u32)va[2][k] | ((u32)va[3][k]<<16);                              \
      *(u32x2*)&Vt[(CUR)^1][d*64 + c*8 + (vr0&7)] = w;                         \
    }                                                                          \
  }                                                                            \
  __builtin_amdgcn_s_setprio(1);                                               \
  _Pragma("unroll")                                                            \
  for (int B=0;B<2;B++){                                                       \
    short8 pa[2];                                                              \
    _Pragma("unroll")                                                          \
    for (int g=0; g<2; ++g)                                                    \
      pa[g] = *(const short8*)&Pl[wv][(g*16+lr16)*64 + (((B<<2)+lg)^(lr16&7))*8]; \
    _Pragma("unroll")                                                          \
    for (int db=0;db<4;db++){                                                  \
      int d = db*16 + lr16;                                                    \
      short8 vf = *(const short8*)&Vt[CUR][d*64 + ((((B<<2)+lg)^(d&7))^((d>>3)&7))*8]; \
      O[0][db] = MFMA(pa[0], vf, O[0][db]);                                    \
      O[1][db] = MFMA(pa[1], vf, O[1][db]);                                    \
    }                                                                          \
  }                                                                            \
  __builtin_amdgcn_s_setprio(0);                                               \
  __syncthreads();                                                             \
}while(0)

__global__ __launch_bounds__(256) void k_attn(const u16* __restrict__ qkv,
                                              u16* __restrict__ o, int T){
  __shared__ __align__(16) u16 Ks[2][64*64];
  __shared__ __align__(16) u16 Vt[2][64*64];
  __shared__ __align__(16) u16 Pl[4][32*64];
  int tid = threadIdx.x, lane = tid&63, wv = tid>>6;
  int bh = blockIdx.x;
  int b = bh>>4, h = bh&15;
  int hq = h*192;
  size_t bt0 = (size_t)b*T;
  int lr16 = lane&15, lg = lane>>4;
  int rx = lr16&7;
  int vr0 = (tid>>4)*4, vd0 = (tid&15)*4;             // V: 4 rows x 4 d per thread
  int kr  = tid>>3;                                    // K: row within 32-half
  int kcs = ((tid&7) ^ (kr&7))*8;                      // pre-swizzled source col
  u16x4 va[4];
  const float QS = 0.18033688f;                        // 0.125 * log2(e)

  #pragma unroll 1
  for (int half=0; half<2; ++half){
    int qt = half ? (int)blockIdx.y : 15 - (int)blockIdx.y;
    int qbase = qt*128;
    // Q fragments (B-operand of swapped QK^T); exp2-domain scale
    short8 qf[2][2];
    #pragma unroll
    for (int g=0; g<2; ++g){
      const u16* qp = qkv + (bt0 + qbase + wv*32 + g*16 + lr16)*3072 + hq + lg*8;
      #pragma unroll
      for (int t=0;t<2;t++){
        u16x8 v = *(const u16x8*)(qp + t*32);
        #pragma unroll
        for (int j=0;j<8;j++) v[j] = f2bf(bf2f(v[j])*QS);
        qf[g][t] = __builtin_bit_cast(short8, v);
      }
    }
    f32x4 O[2][4] = {};
    float m_run[2] = {-1e30f,-1e30f}, l_run[2] = {0.f,0.f};
    int qglob[2] = {qbase + wv*32 + lr16, qbase + wv*32 + 16 + lr16};

    // prologue: stage tile 0 into buffer 0
    {
      #pragma unroll
      for (int i=0;i<4;i++)
        va[i] = *(const u16x4*)(qkv + (bt0 + vr0 + i)*3072 + hq + 128 + vd0);
      #pragma unroll
      for (int p=0;p<2;p++){
        int row = p*32 + kr;
        gld_lds16(qkv + (bt0+row)*3072 + hq + 64 + kcs, &Ks[0][p*2048 + tid*8]);
      }
      #pragma unroll
      for (int k=0;k<4;k++){
        int d = vd0+k;
        int c = (vr0>>3) ^ (d&7) ^ ((d>>3)&7);
        u32x2 w;
        w[0] = (u32)va[0][k] | ((u32)va[1][k]<<16);
        w[1] = (u32)va[2][k] | ((u32)va[3][k]<<16);
        *(u32x2*)&Vt[0][d*64 + c*8 + (vr0&7)] = w;
      }
    }
    __syncthreads();

    int nkv = 2*qt + 2;   // always even
    #pragma unroll 1
    for (int kb=0; kb<nkv; kb+=2){
      ATTN_ITER(kb,   0, true);
      ATTN_ITER(kb+1, 1, (kb+2<nkv));
    }
    // writeout (rcp instead of div)
    #pragma unroll
    for (int g=0; g<2; ++g){
      float lrow[4];
      #pragma unroll
      for (int j=0;j<4;j++) lrow[j] = __builtin_amdgcn_rcpf(__shfl(l_run[g], lg*4 + j));
      #pragma unroll
      for (int db=0;db<4;db++)
        #pragma unroll
        for (int j=0;j<4;j++){
          size_t row = bt0 + qbase + wv*32 + g*16 + lg*4 + j;
          o[row*1024 + h*64 + db*16 + lr16] = f2bf(O[g][db][j] * lrow[j]);
        }
    }
  }
}

extern "C" void kernel_launch(void* const* d_in, const int* in_sizes, int n_in,
                              void* d_out, int out_size, void* d_ws, size_t ws_size,
                              hipStream_t stream){
  (void)in_sizes; (void)n_in; (void)out_size; (void)ws_size;
  const float* x     = (const float*)d_in[0];
  const float* Wqkv  = (const float*)d_in[1];
  const float* bqkv  = (const float*)d_in[2];
  const float* Wproj = (const float*)d_in[3];
  const float* bproj = (const float*)d_in[4];
  float* out = (float*)d_out;
  const int B=4, T=2048, C=1024;
  const int M = B*T; // 8192
  char* ws = (char*)d_ws;
  u16* qkvb   = (u16*)(ws);                 // 8192*3072 bf16 = 50331648 B
  u16* attnb  = (u16*)(ws + 50331648);      // 8192*1024 bf16 = 16777216 B
  u16* xb     = (u16*)(ws + 67108864);      // 8192*1024 bf16 = 16777216 B
  u16* wqkvT  = (u16*)(ws + 83886080);      // 3072*1024 bf16 =  6291456 B
  u16* wprojT = (u16*)(ws + 90177536);      // 1024*1024 bf16 =  2097152 B

  k_cast_x<<<4096, 256, 0, stream>>>(x, xb, M*C/8);
  dim3 tb(32,8);
  k_transpose_cast<<<dim3(96,32), tb, 0, stream>>>(Wqkv, wqkvT, C, 3*C);
  k_transpose_cast<<<dim3(32,32), tb, 0, stream>>>(Wproj, wprojT, C, C);
  gemm_bt<1><<<dim3(24,64), 256, 0, stream>>>(xb, wqkvT, bqkv, qkvb, M, 3*C, C);
  k_attn<<<dim3(64,8), 256, 0, stream>>>(qkvb, attnb, T);
  gemm_bt<0><<<dim3(8,64), 256, 0, stream>>>(attnb, wprojT, bproj, out, M, C, C);
}

// Round 9
// 203.641 us; speedup vs baseline: 2.3492x; 1.0989x over previous
//
#include <hip/hip_runtime.h>

typedef unsigned short u16;
typedef unsigned int u32;
typedef __attribute__((ext_vector_type(8))) short short8;
typedef __attribute__((ext_vector_type(8))) unsigned short u16x8;
typedef __attribute__((ext_vector_type(4))) unsigned short u16x4;
typedef __attribute__((ext_vector_type(2))) unsigned int u32x2;
typedef __attribute__((ext_vector_type(4))) float f32x4;

__device__ __forceinline__ u16 f2bf(float f){
  u32 u = __builtin_bit_cast(u32, f);
  u32 r = u + 0x7FFFu + ((u >> 16) & 1u);
  return (u16)(r >> 16);
}
__device__ __forceinline__ float bf2f(u16 h){
  u32 u = ((u32)h) << 16;
  return __builtin_bit_cast(float, u);
}
__device__ __forceinline__ float f3max(float a, float b, float c){
  return fmaxf(a, fmaxf(b, c));   // fuses to v_max3_f32
}
__device__ __forceinline__ u32 cvtpk(float lo, float hi){
  u32 r;
  asm("v_cvt_pk_bf16_f32 %0, %1, %2" : "=v"(r) : "v"(lo), "v"(hi));
  return r;
}

__device__ __forceinline__ void gld_lds16(const u16* g, u16* l){
  __builtin_amdgcn_global_load_lds(
      (const __attribute__((address_space(1))) u32*)g,
      (__attribute__((address_space(3))) u32*)l, 16, 0, 0);
}

#define MFMA(a,b,c) __builtin_amdgcn_mfma_f32_16x16x32_bf16((a),(b),(c),0,0,0)

// ---------------- cast x (f32 -> bf16), 8 elems/thread ----------------
__global__ void k_cast_x(const float* __restrict__ in, u16* __restrict__ out, int n8){
  int i = blockIdx.x*256 + threadIdx.x;
  if (i >= n8) return;
  const float4 a = ((const float4*)in)[2*i];
  const float4 b = ((const float4*)in)[2*i+1];
  u16x8 o;
  o[0]=f2bf(a.x); o[1]=f2bf(a.y); o[2]=f2bf(a.z); o[3]=f2bf(a.w);
  o[4]=f2bf(b.x); o[5]=f2bf(b.y); o[6]=f2bf(b.z); o[7]=f2bf(b.w);
  ((u16x8*)out)[i] = o;
}

// ---------------- transpose + cast: in[R][C] f32 -> out[C][R] bf16 ----------------
__global__ void k_transpose_cast(const float* __restrict__ in, u16* __restrict__ out,
                                 int R, int C){
  __shared__ float tile[32][33];
  int c0 = blockIdx.x*32, r0 = blockIdx.y*32;
  int tx = threadIdx.x, ty = threadIdx.y; // block (32,8)
  #pragma unroll
  for (int i=0;i<4;i++) tile[ty+8*i][tx] = in[(size_t)(r0+ty+8*i)*C + c0+tx];
  __syncthreads();
  #pragma unroll
  for (int i=0;i<4;i++) out[(size_t)(c0+ty+8*i)*R + r0+tx] = f2bf(tile[tx][ty+8*i]);
}

// ---------------- GEMM: C[M][N] = A[M][K](bf16) * Bt[N][K](bf16) + bias[N] ----------------
// 128x128 tile, BK=32, 4 waves, m97 structure + XCD-aware block swizzle (T1).
template<int OUT_BF16>
__global__ __launch_bounds__(256) void gemm_bt(const u16* __restrict__ A,
                                               const u16* __restrict__ Bt,
                                               const float* __restrict__ bias,
                                               void* __restrict__ Cp,
                                               int M, int N, int K){
  __shared__ __align__(16) u16 As[128*32];
  __shared__ __align__(16) u16 Bs[128*32];
  int tid = threadIdx.x, lane = tid&63, wv = tid>>6;
  int wr = wv>>1, wc = wv&1;
  int lr16 = lane&15, lg = lane>>4;
  // XCD swizzle (grid size % 8 == 0 for both GEMMs)
  int nwg = gridDim.x*gridDim.y;
  int lin = blockIdx.y*gridDim.x + blockIdx.x;
  int cpx = nwg>>3;
  int swz = (lin&7)*cpx + (lin>>3);
  int bx = swz % gridDim.x, by = swz / gridDim.x;
  size_t brow = (size_t)by*128, bcol = (size_t)bx*128;
  f32x4 acc[4][4] = {};
  int nk = K>>5;
  for (int kt=0; kt<nk; ++kt){
    int k0 = kt*32;
    #pragma unroll
    for (int c=0;c<2;c++){
      gld_lds16(A  + (brow + c*64 + (tid>>2))*K + k0 + (tid&3)*8, &As[c*2048 + tid*8]);
      gld_lds16(Bt + (bcol + c*64 + (tid>>2))*K + k0 + (tid&3)*8, &Bs[c*2048 + tid*8]);
    }
    __syncthreads();
    short8 af[4], bfr[4];
    #pragma unroll
    for (int m=0;m<4;m++) af[m]  = *(const short8*)&As[(wr*64 + m*16 + lr16)*32 + lg*8];
    #pragma unroll
    for (int n=0;n<4;n++) bfr[n] = *(const short8*)&Bs[(wc*64 + n*16 + lr16)*32 + lg*8];
    #pragma unroll
    for (int m=0;m<4;m++)
      #pragma unroll
      for (int n=0;n<4;n++) acc[m][n] = MFMA(af[m], bfr[n], acc[m][n]);
    __syncthreads();
  }
  #pragma unroll
  for (int n=0;n<4;n++){
    size_t col = bcol + wc*64 + n*16 + lr16;
    float bs = bias[col];
    #pragma unroll
    for (int m=0;m<4;m++)
      #pragma unroll
      for (int j=0;j<4;j++){
        size_t row = brow + wr*64 + m*16 + lg*4 + j;
        float v = acc[m][n][j] + bs;
        if (OUT_BF16) ((u16*)Cp)[row*(size_t)N + col] = f2bf(v);
        else          ((float*)Cp)[row*(size_t)N + col] = v;
      }
  }
}

// ---------------- flash attention, causal, hs=64, H=16 ----------------
// 8 waves x 512 threads, QBLK=128 (16 q/wave), KVBLK=64. Each block processes
// TWO q-tiles (qt = 15-y then qt = y): 512 equal blocks = 2/CU = 16 waves/CU.
// Double-buffered K/V, async stage split, kv-loop unrolled by 2 (literal CUR).
// Softmax in exp2 domain; defer-max THR=8; l-sum via MFMA ones-trick (acc_l).
// Swizzles: Ks chunk^=row&7 (pre-swizzled gld_lds source);
//           Vt[d][kv] chunk^=(d&7)^((d>>3)&7); Pl[q][kv] chunk^=q&7.
#define ATTN_ITER(KB, CUR, PF) do{                                             \
  int kv0 = (KB)*64;                                                           \
  if (PF){                                                                     \
    int kv1 = kv0 + 64;                                                        \
    va[0] = *(const u16x4*)(qkv + (bt0 + kv1 + vr0    )*3072 + hq + 128 + vd0);\
    va[1] = *(const u16x4*)(qkv + (bt0 + kv1 + vr0 + 1)*3072 + hq + 128 + vd0);\
    gld_lds16(qkv + (bt0+kv1+kr)*3072 + hq + 64 + kcs, &Ks[(CUR)^1][tid*8]);   \
  }                                                                            \
  f32x4 st[4];                                                                 \
  __builtin_amdgcn_s_setprio(1);                                               \
  _Pragma("unroll")                                                            \
  for (int s=0;s<4;s++){                                                       \
    short8 kf0 = *(const short8*)&Ks[CUR][(s*16+lr16)*64 + ((lg  )^rx)*8];     \
    short8 kf1 = *(const short8*)&Ks[CUR][(s*16+lr16)*64 + ((4+lg)^rx)*8];     \
    f32x4 z = {0,0,0,0};                                                       \
    z = MFMA(kf0, qf[0], z);                                                   \
    z = MFMA(kf1, qf[1], z);                                                   \
    st[s] = z;                                                                 \
  }                                                                            \
  __builtin_amdgcn_s_setprio(0);                                               \
  if (kv0 >= qbase){                                                           \
    _Pragma("unroll")                                                          \
    for (int s=0;s<4;s++)                                                      \
      _Pragma("unroll")                                                        \
      for (int j=0;j<4;j++){                                                   \
        int kvg = kv0 + s*16 + lg*4 + j;                                       \
        if (kvg > qglob) st[s][j] = -1e30f;                                    \
      }                                                                        \
  }                                                                            \
  {                                                                            \
    float mx = f3max(st[0][0], st[0][1], st[0][2]);                            \
    mx = f3max(mx, st[0][3], st[1][0]);                                        \
    mx = f3max(mx, st[1][1], st[1][2]);                                        \
    mx = f3max(mx, st[1][3], st[2][0]);                                        \
    mx = f3max(mx, st[2][1], st[2][2]);                                        \
    mx = f3max(mx, st[2][3], st[3][0]);                                        \
    mx = f3max(mx, st[3][1], st[3][2]);                                        \
    mx = fmaxf(mx, st[3][3]);                                                  \
    mx = fmaxf(mx, __shfl_xor(mx, 16));                                        \
    mx = fmaxf(mx, __shfl_xor(mx, 32));                                        \
    if (__any(mx > m_run + 8.f)){                                              \
      float m_new = fmaxf(m_run, mx);                                          \
      float al = exp2f(m_run - m_new);                                         \
      m_run = m_new;                                                           \
      float arow[4];                                                           \
      _Pragma("unroll")                                                        \
      for (int j=0;j<4;j++) arow[j] = __shfl(al, lg*4 + j);                    \
      _Pragma("unroll")                                                        \
      for (int db=0;db<4;db++)                                                 \
        _Pragma("unroll")                                                      \
        for (int j=0;j<4;j++) O[db][j] *= arow[j];                             \
      _Pragma("unroll")                                                        \
      for (int j=0;j<4;j++) acc_l[j] *= arow[j];                               \
    }                                                                          \
    float mr = m_run;                                                          \
    u32 pw[8];                                                                 \
    _Pragma("unroll")                                                          \
    for (int s=0;s<4;s++){                                                     \
      float p0 = exp2f(st[s][0]-mr), p1 = exp2f(st[s][1]-mr);                  \
      float p2 = exp2f(st[s][2]-mr), p3 = exp2f(st[s][3]-mr);                  \
      pw[s*2+0] = cvtpk(p0,p1);                                                \
      pw[s*2+1] = cvtpk(p2,p3);                                                \
    }                                                                          \
    _Pragma("unroll")                                                          \
    for (int s=0;s<4;s++){                                                     \
      int cp = (s*2 + (lg>>1)) ^ rx;                                           \
      u32x2 w2; w2[0] = pw[s*2]; w2[1] = pw[s*2+1];                            \
      *(u32x2*)&Pl[wv][lr16*64 + cp*8 + (lg&1)*4] = w2;                        \
    }                                                                          \
  }                                                                            \
  if (PF){                                                                     \
    _Pragma("unroll")                                                          \
    for (int k=0;k<4;k++){                                                     \
      int d = vd0+k;                                                           \
      int c = (vr0>>3) ^ (d&7) ^ ((d>>3)&7);                                   \
      u32 w = (u32)va[0][k] | ((u32)va[1][k]<<16);                             \
      *(u32*)&Vt[(CUR)^1][d*64 + c*8 + (vr0&7)] = w;                           \
    }                                                                          \
  }                                                                            \
  __builtin_amdgcn_s_setprio(1);                                               \
  _Pragma("unroll")                                                            \
  for (int B=0;B<2;B++){                                                       \
    short8 pa = *(const short8*)&Pl[wv][lr16*64 + (((B<<2)+lg)^rx)*8];         \
    acc_l = MFMA(pa, onesf, acc_l);                                            \
    _Pragma("unroll")                                                          \
    for (int db=0;db<4;db++){                                                  \
      int d = db*16 + lr16;                                                    \
      short8 vf = *(const short8*)&Vt[CUR][d*64 + ((((B<<2)+lg)^(d&7))^((d>>3)&7))*8]; \
      O[db] = MFMA(pa, vf, O[db]);                                             \
    }                                                                          \
  }                                                                            \
  __builtin_amdgcn_s_setprio(0);                                               \
  __syncthreads();                                                             \
}while(0)

__global__ __launch_bounds__(512, 4) void k_attn(const u16* __restrict__ qkv,
                                                 u16* __restrict__ o, int T){
  __shared__ __align__(16) u16 Ks[2][64*64];
  __shared__ __align__(16) u16 Vt[2][64*64];
  __shared__ __align__(16) u16 Pl[8][16*64];
  int tid = threadIdx.x, lane = tid&63, wv = tid>>6;
  int bh = blockIdx.x;
  int b = bh>>4, h = bh&15;
  int hq = h*192;
  size_t bt0 = (size_t)b*T;
  int lr16 = lane&15, lg = lane>>4;
  int rx = lr16&7;
  int vr0 = (tid>>4)*2, vd0 = (tid&15)*4;             // V: 2 rows x 4 d per thread
  int kr  = tid>>3;                                    // K: row (512 thr -> 64 rows)
  int kcs = ((tid&7) ^ (kr&7))*8;                      // pre-swizzled source col
  u16x4 va[2];
  const float QS = 0.18033688f;                        // 0.125 * log2(e)
  u16x8 ov;
  #pragma unroll
  for (int j=0;j<8;j++) ov[j] = 0x3F80;                // bf16 1.0
  const short8 onesf = __builtin_bit_cast(short8, ov);

  #pragma unroll 1
  for (int half=0; half<2; ++half){
    int qt = half ? (int)blockIdx.y : 15 - (int)blockIdx.y;
    int qbase = qt*128;
    // Q fragments (B-operand of swapped QK^T); exp2-domain scale
    short8 qf[2];
    {
      const u16* qp = qkv + (bt0 + qbase + wv*16 + lr16)*3072 + hq + lg*8;
      #pragma unroll
      for (int t=0;t<2;t++){
        u16x8 v = *(const u16x8*)(qp + t*32);
        #pragma unroll
        for (int j=0;j<8;j++) v[j] = f2bf(bf2f(v[j])*QS);
        qf[t] = __builtin_bit_cast(short8, v);
      }
    }
    f32x4 O[4] = {};
    f32x4 acc_l = {0,0,0,0};
    float m_run = -1e30f;
    int qglob = qbase + wv*16 + lr16;

    // prologue: stage tile 0 into buffer 0
    {
      va[0] = *(const u16x4*)(qkv + (bt0 + vr0    )*3072 + hq + 128 + vd0);
      va[1] = *(const u16x4*)(qkv + (bt0 + vr0 + 1)*3072 + hq + 128 + vd0);
      gld_lds16(qkv + (bt0+kr)*3072 + hq + 64 + kcs, &Ks[0][tid*8]);
      #pragma unroll
      for (int k=0;k<4;k++){
        int d = vd0+k;
        int c = (vr0>>3) ^ (d&7) ^ ((d>>3)&7);
        u32 w = (u32)va[0][k] | ((u32)va[1][k]<<16);
        *(u32*)&Vt[0][d*64 + c*8 + (vr0&7)] = w;
      }
    }
    __syncthreads();

    int nkv = 2*qt + 2;   // always even
    #pragma unroll 1
    for (int kb=0; kb<nkv; kb+=2){
      ATTN_ITER(kb,   0, true);
      ATTN_ITER(kb+1, 1, (kb+2<nkv));
    }
    // writeout: acc_l fragment already has l for row lg*4+j (no shuffle needed)
    {
      float lrow[4];
      #pragma unroll
      for (int j=0;j<4;j++) lrow[j] = __builtin_amdgcn_rcpf(acc_l[j]);
      #pragma unroll
      for (int db=0;db<4;db++)
        #pragma unroll
        for (int j=0;j<4;j++){
          size_t row = bt0 + qbase + wv*16 + lg*4 + j;
          o[row*1024 + h*64 + db*16 + lr16] = f2bf(O[db][j] * lrow[j]);
        }
    }
  }
}

extern "C" void kernel_launch(void* const* d_in, const int* in_sizes, int n_in,
                              void* d_out, int out_size, void* d_ws, size_t ws_size,
                              hipStream_t stream){
  (void)in_sizes; (void)n_in; (void)out_size; (void)ws_size;
  const float* x     = (const float*)d_in[0];
  const float* Wqkv  = (const float*)d_in[1];
  const float* bqkv  = (const float*)d_in[2];
  const float* Wproj = (const float*)d_in[3];
  const float* bproj = (const float*)d_in[4];
  float* out = (float*)d_out;
  const int B=4, T=2048, C=1024;
  const int M = B*T; // 8192
  char* ws = (char*)d_ws;
  u16* qkvb   = (u16*)(ws);                 // 8192*3072 bf16 = 50331648 B
  u16* attnb  = (u16*)(ws + 50331648);      // 8192*1024 bf16 = 16777216 B
  u16* xb     = (u16*)(ws + 67108864);      // 8192*1024 bf16 = 16777216 B
  u16* wqkvT  = (u16*)(ws + 83886080);      // 3072*1024 bf16 =  6291456 B
  u16* wprojT = (u16*)(ws + 90177536);      // 1024*1024 bf16 =  2097152 B

  k_cast_x<<<4096, 256, 0, stream>>>(x, xb, M*C/8);
  dim3 tb(32,8);
  k_transpose_cast<<<dim3(96,32), tb, 0, stream>>>(Wqkv, wqkvT, C, 3*C);
  k_transpose_cast<<<dim3(32,32), tb, 0, stream>>>(Wproj, wprojT, C, C);
  gemm_bt<1><<<dim3(24,64), 256, 0, stream>>>(xb, wqkvT, bqkv, qkvb, M, 3*C, C);
  k_attn<<<dim3(64,8), 512, 0, stream>>>(qkvb, attnb, T);
  gemm_bt<0><<<dim3(8,64), 256, 0, stream>>>(attnb, wprojT, bproj, out, M, C, C);
}

// Round 10
// 188.287 us; speedup vs baseline: 2.5408x; 1.0815x over previous
//
#include <hip/hip_runtime.h>

typedef unsigned short u16;
typedef unsigned int u32;
typedef __attribute__((ext_vector_type(8))) short short8;
typedef __attribute__((ext_vector_type(8))) unsigned short u16x8;
typedef __attribute__((ext_vector_type(4))) unsigned short u16x4;
typedef __attribute__((ext_vector_type(2))) unsigned int u32x2;
typedef __attribute__((ext_vector_type(4))) float f32x4;

__device__ __forceinline__ u16 f2bf(float f){
  u32 u = __builtin_bit_cast(u32, f);
  u32 r = u + 0x7FFFu + ((u >> 16) & 1u);
  return (u16)(r >> 16);
}
__device__ __forceinline__ float bf2f(u16 h){
  u32 u = ((u32)h) << 16;
  return __builtin_bit_cast(float, u);
}
__device__ __forceinline__ float f3max(float a, float b, float c){
  return fmaxf(a, fmaxf(b, c));   // fuses to v_max3_f32
}
__device__ __forceinline__ u32 cvtpk(float lo, float hi){
  u32 r;
  asm("v_cvt_pk_bf16_f32 %0, %1, %2" : "=v"(r) : "v"(lo), "v"(hi));
  return r;
}

__device__ __forceinline__ void gld_lds16(const u16* g, u16* l){
  __builtin_amdgcn_global_load_lds(
      (const __attribute__((address_space(1))) u32*)g,
      (__attribute__((address_space(3))) u32*)l, 16, 0, 0);
}

#define MFMA(a,b,c) __builtin_amdgcn_mfma_f32_16x16x32_bf16((a),(b),(c),0,0,0)

// ---------------- cast x (f32 -> bf16), 8 elems/thread ----------------
__global__ void k_cast_x(const float* __restrict__ in, u16* __restrict__ out, int n8){
  int i = blockIdx.x*256 + threadIdx.x;
  if (i >= n8) return;
  const float4 a = ((const float4*)in)[2*i];
  const float4 b = ((const float4*)in)[2*i+1];
  u16x8 o;
  o[0]=f2bf(a.x); o[1]=f2bf(a.y); o[2]=f2bf(a.z); o[3]=f2bf(a.w);
  o[4]=f2bf(b.x); o[5]=f2bf(b.y); o[6]=f2bf(b.z); o[7]=f2bf(b.w);
  ((u16x8*)out)[i] = o;
}

// ---------------- transpose + cast: in[R][C] f32 -> out[C][R] bf16 ----------------
__global__ void k_transpose_cast(const float* __restrict__ in, u16* __restrict__ out,
                                 int R, int C){
  __shared__ float tile[32][33];
  int c0 = blockIdx.x*32, r0 = blockIdx.y*32;
  int tx = threadIdx.x, ty = threadIdx.y; // block (32,8)
  #pragma unroll
  for (int i=0;i<4;i++) tile[ty+8*i][tx] = in[(size_t)(r0+ty+8*i)*C + c0+tx];
  __syncthreads();
  #pragma unroll
  for (int i=0;i<4;i++) out[(size_t)(c0+ty+8*i)*R + r0+tx] = f2bf(tile[tx][ty+8*i]);
}

// ---------------- GEMM (proj): C[M][N] = A*Bt + bias, 128x128 m97-structure ----------------
template<int OUT_BF16>
__global__ __launch_bounds__(256) void gemm_bt(const u16* __restrict__ A,
                                               const u16* __restrict__ Bt,
                                               const float* __restrict__ bias,
                                               void* __restrict__ Cp,
                                               int M, int N, int K){
  __shared__ __align__(16) u16 As[128*32];
  __shared__ __align__(16) u16 Bs[128*32];
  int tid = threadIdx.x, lane = tid&63, wv = tid>>6;
  int wr = wv>>1, wc = wv&1;
  int lr16 = lane&15, lg = lane>>4;
  int nwg = gridDim.x*gridDim.y;
  int lin = blockIdx.y*gridDim.x + blockIdx.x;
  int cpx = nwg>>3;
  int swz = (lin&7)*cpx + (lin>>3);
  int bx = swz % gridDim.x, by = swz / gridDim.x;
  size_t brow = (size_t)by*128, bcol = (size_t)bx*128;
  f32x4 acc[4][4] = {};
  int nk = K>>5;
  for (int kt=0; kt<nk; ++kt){
    int k0 = kt*32;
    #pragma unroll
    for (int c=0;c<2;c++){
      gld_lds16(A  + (brow + c*64 + (tid>>2))*K + k0 + (tid&3)*8, &As[c*2048 + tid*8]);
      gld_lds16(Bt + (bcol + c*64 + (tid>>2))*K + k0 + (tid&3)*8, &Bs[c*2048 + tid*8]);
    }
    __syncthreads();
    short8 af[4], bfr[4];
    #pragma unroll
    for (int m=0;m<4;m++) af[m]  = *(const short8*)&As[(wr*64 + m*16 + lr16)*32 + lg*8];
    #pragma unroll
    for (int n=0;n<4;n++) bfr[n] = *(const short8*)&Bs[(wc*64 + n*16 + lr16)*32 + lg*8];
    #pragma unroll
    for (int m=0;m<4;m++)
      #pragma unroll
      for (int n=0;n<4;n++) acc[m][n] = MFMA(af[m], bfr[n], acc[m][n]);
    __syncthreads();
  }
  #pragma unroll
  for (int n=0;n<4;n++){
    size_t col = bcol + wc*64 + n*16 + lr16;
    float bs = bias[col];
    #pragma unroll
    for (int m=0;m<4;m++)
      #pragma unroll
      for (int j=0;j<4;j++){
        size_t row = brow + wr*64 + m*16 + lg*4 + j;
        float v = acc[m][n][j] + bs;
        if (OUT_BF16) ((u16*)Cp)[row*(size_t)N + col] = f2bf(v);
        else          ((float*)Cp)[row*(size_t)N + col] = v;
      }
  }
}

// ---------------- 256x256 8-phase GEMM (QKV): C[M][3072] = A[M][1024]*Bt[3072][1024] ----------------
// 8 waves (2Mx4N), BK=64, double-buffered 128KB LDS, T2 swizzle (chunk^=row&7,
// pre-swizzled gld_lds source), per-phase raw barriers + setprio MFMA clusters,
// single vmcnt(0) per K-tile (stages front-loaded in phases 0-1).
#define G_STAGE(PTR, BROW, LDS, T_, BUF) do{                                   \
  size_t k0_ = (size_t)(T_)*64;                                                \
  _Pragma("unroll")                                                            \
  for (int l=0;l<4;l++){                                                       \
    int r_ = (l&1)*64 + (tid>>3);                                              \
    int h_ = l>>1;                                                             \
    gld_lds16(PTR + (size_t)((BROW) + h_*128 + r_)*1024 + k0_ + (((tid&7)^(r_&7))*8), \
              &LDS[(BUF)*16384 + h_*8192 + (l&1)*4096 + tid*8]);               \
  }                                                                            \
}while(0)

#define RD_A(MQ, CUR) do{                                                      \
  _Pragma("unroll")                                                            \
  for (int m=0;m<4;m++)                                                        \
    _Pragma("unroll")                                                          \
    for (int k=0;k<2;k++){                                                     \
      int hr = (MQ)*64 + m*16 + lr16;                                          \
      af[m][k] = *(const short8*)&Alds[(CUR)*16384 + wr*8192 + hr*64 + (((k*4+lg)^(hr&7))*8)]; \
    }                                                                          \
}while(0)

#define RD_B(NQ, CUR) do{                                                      \
  _Pragma("unroll")                                                            \
  for (int n=0;n<2;n++)                                                        \
    _Pragma("unroll")                                                          \
    for (int k=0;k<2;k++){                                                     \
      int hr = (wc&1)*64 + ((NQ)*2+n)*16 + lr16;                               \
      bfv[(NQ)*2+n][k] = *(const short8*)&Blds[(CUR)*16384 + (wc>>1)*8192 + hr*64 + (((k*4+lg)^(hr&7))*8)]; \
    }                                                                          \
}while(0)

#define MF16(MQ, NQ)                                                           \
  _Pragma("unroll")                                                            \
  for (int k=0;k<2;k++)                                                        \
    _Pragma("unroll")                                                          \
    for (int m=0;m<4;m++)                                                      \
      _Pragma("unroll")                                                        \
      for (int n=0;n<2;n++)                                                    \
        acc[(MQ)*4+m][(NQ)*2+n] = MFMA(af[m][k], bfv[(NQ)*2+n][k], acc[(MQ)*4+m][(NQ)*2+n]);

#define G_TILE(T_, CUR, PF) do{                                                \
  RD_A(0, CUR); RD_B(0, CUR);                                                  \
  if (PF) G_STAGE(Ag, brow, Alds, (T_)+1, (CUR)^1);                            \
  __builtin_amdgcn_s_barrier();                                                \
  __builtin_amdgcn_s_setprio(1); MF16(0,0); __builtin_amdgcn_s_setprio(0);     \
  __builtin_amdgcn_s_barrier();                                                \
  RD_B(1, CUR);                                                                \
  if (PF) G_STAGE(Bg, bcol, Blds, (T_)+1, (CUR)^1);                            \
  __builtin_amdgcn_s_barrier();                                                \
  __builtin_amdgcn_s_setprio(1); MF16(0,1); __builtin_amdgcn_s_setprio(0);     \
  __builtin_amdgcn_s_barrier();                                                \
  RD_A(1, CUR);                                                                \
  __builtin_amdgcn_s_barrier();                                                \
  __builtin_amdgcn_s_setprio(1); MF16(1,1); __builtin_amdgcn_s_setprio(0);     \
  __builtin_amdgcn_s_barrier();                                                \
  __builtin_amdgcn_s_setprio(1); MF16(1,0); __builtin_amdgcn_s_setprio(0);     \
  asm volatile("s_waitcnt vmcnt(0)" ::: "memory");                             \
  __builtin_amdgcn_sched_barrier(0);                                           \
  __builtin_amdgcn_s_barrier();                                                \
}while(0)

__global__ __launch_bounds__(512) void gemm256(const u16* __restrict__ Ag,
                                               const u16* __restrict__ Bg,
                                               const float* __restrict__ bias,
                                               u16* __restrict__ Cp, int N){
  extern __shared__ u16 lds[];
  u16* Alds = lds;            // 2 x 16384 elems
  u16* Blds = lds + 32768;    // 2 x 16384 elems
  int tid = threadIdx.x, lane = tid&63, wid = tid>>6;
  int wr = wid>>2, wc = wid&3;
  int lr16 = lane&15, lg = lane>>4;
  int nbx = gridDim.x;
  int nwg = nbx*gridDim.y;
  int lin = blockIdx.y*nbx + blockIdx.x;
  int cpx = nwg>>3;
  int swz = (lin&7)*cpx + (lin>>3);
  int bx = swz % nbx, by = swz / nbx;
  size_t brow = (size_t)by*256, bcol = (size_t)bx*256;
  f32x4 acc[8][4] = {};
  short8 af[4][2], bfv[4][2];

  G_STAGE(Ag, brow, Alds, 0, 0);
  G_STAGE(Bg, bcol, Blds, 0, 0);
  __syncthreads();

  #pragma unroll 1
  for (int kt=0; kt<16; kt+=2){
    G_TILE(kt,   0, true);
    G_TILE(kt+1, 1, (kt+2<16));
  }

  #pragma unroll
  for (int n=0;n<4;n++){
    size_t col = bcol + wc*64 + n*16 + lr16;
    float bs = bias[col];
    #pragma unroll
    for (int mi=0;mi<8;mi++)
      #pragma unroll
      for (int j=0;j<4;j++){
        size_t row = brow + wr*128 + mi*16 + lg*4 + j;
        Cp[row*(size_t)N + col] = f2bf(acc[mi][n][j] + bs);
      }
  }
}

// ---------------- flash attention, causal, hs=64, H=16 ----------------
// 8 waves x 512 threads, QBLK=128 (16 q/wave), KVBLK=64. Each block processes
// TWO q-tiles (qt = 15-y then qt = y): 512 equal blocks = 2/CU = 16 waves/CU.
// Double-buffered K/V, async stage split, kv-loop unrolled by 2 (literal CUR).
// Softmax in exp2 domain; defer-max THR=8; l-sum via MFMA ones-trick (acc_l).
#define ATTN_ITER(KB, CUR, PF) do{                                             \
  int kv0 = (KB)*64;                                                           \
  if (PF){                                                                     \
    int kv1 = kv0 + 64;                                                        \
    va[0] = *(const u16x4*)(qkv + (bt0 + kv1 + vr0    )*3072 + hq + 128 + vd0);\
    va[1] = *(const u16x4*)(qkv + (bt0 + kv1 + vr0 + 1)*3072 + hq + 128 + vd0);\
    gld_lds16(qkv + (bt0+kv1+kr)*3072 + hq + 64 + kcs, &Ks[(CUR)^1][tid*8]);   \
  }                                                                            \
  f32x4 st[4];                                                                 \
  __builtin_amdgcn_s_setprio(1);                                               \
  _Pragma("unroll")                                                            \
  for (int s=0;s<4;s++){                                                       \
    short8 kf0 = *(const short8*)&Ks[CUR][(s*16+lr16)*64 + ((lg  )^rx)*8];     \
    short8 kf1 = *(const short8*)&Ks[CUR][(s*16+lr16)*64 + ((4+lg)^rx)*8];     \
    f32x4 z = {0,0,0,0};                                                       \
    z = MFMA(kf0, qf[0], z);                                                   \
    z = MFMA(kf1, qf[1], z);                                                   \
    st[s] = z;                                                                 \
  }                                                                            \
  __builtin_amdgcn_s_setprio(0);                                               \
  if (kv0 >= qbase){                                                           \
    _Pragma("unroll")                                                          \
    for (int s=0;s<4;s++)                                                      \
      _Pragma("unroll")                                                        \
      for (int j=0;j<4;j++){                                                   \
        int kvg = kv0 + s*16 + lg*4 + j;                                       \
        if (kvg > qglob) st[s][j] = -1e30f;                                    \
      }                                                                        \
  }                                                                            \
  {                                                                            \
    float mx = f3max(st[0][0], st[0][1], st[0][2]);                            \
    mx = f3max(mx, st[0][3], st[1][0]);                                        \
    mx = f3max(mx, st[1][1], st[1][2]);                                        \
    mx = f3max(mx, st[1][3], st[2][0]);                                        \
    mx = f3max(mx, st[2][1], st[2][2]);                                        \
    mx = f3max(mx, st[2][3], st[3][0]);                                        \
    mx = f3max(mx, st[3][1], st[3][2]);                                        \
    mx = fmaxf(mx, st[3][3]);                                                  \
    mx = fmaxf(mx, __shfl_xor(mx, 16));                                        \
    mx = fmaxf(mx, __shfl_xor(mx, 32));                                        \
    if (__any(mx > m_run + 8.f)){                                              \
      float m_new = fmaxf(m_run, mx);                                          \
      float al = exp2f(m_run - m_new);                                         \
      m_run = m_new;                                                           \
      float arow[4];                                                           \
      _Pragma("unroll")                                                        \
      for (int j=0;j<4;j++) arow[j] = __shfl(al, lg*4 + j);                    \
      _Pragma("unroll")                                                        \
      for (int db=0;db<4;db++)                                                 \
        _Pragma("unroll")                                                      \
        for (int j=0;j<4;j++) O[db][j] *= arow[j];                             \
      _Pragma("unroll")                                                        \
      for (int j=0;j<4;j++) acc_l[j] *= arow[j];                               \
    }                                                                          \
    float mr = m_run;                                                          \
    u32 pw[8];                                                                 \
    _Pragma("unroll")                                                          \
    for (int s=0;s<4;s++){                                                     \
      float p0 = exp2f(st[s][0]-mr), p1 = exp2f(st[s][1]-mr);                  \
      float p2 = exp2f(st[s][2]-mr), p3 = exp2f(st[s][3]-mr);                  \
      pw[s*2+0] = cvtpk(p0,p1);                                                \
      pw[s*2+1] = cvtpk(p2,p3);                                                \
    }                                                                          \
    _Pragma("unroll")                                                          \
    for (int s=0;s<4;s++){                                                     \
      int cp = (s*2 + (lg>>1)) ^ rx;                                           \
      u32x2 w2; w2[0] = pw[s*2]; w2[1] = pw[s*2+1];                            \
      *(u32x2*)&Pl[wv][lr16*64 + cp*8 + (lg&1)*4] = w2;                        \
    }                                                                          \
  }                                                                            \
  if (PF){                                                                     \
    _Pragma("unroll")                                                          \
    for (int k=0;k<4;k++){                                                     \
      int d = vd0+k;                                                           \
      int c = (vr0>>3) ^ (d&7) ^ ((d>>3)&7);                                   \
      u32 w = (u32)va[0][k] | ((u32)va[1][k]<<16);                             \
      *(u32*)&Vt[(CUR)^1][d*64 + c*8 + (vr0&7)] = w;                           \
    }                                                                          \
  }                                                                            \
  __builtin_amdgcn_s_setprio(1);                                               \
  _Pragma("unroll")                                                            \
  for (int B=0;B<2;B++){                                                       \
    short8 pa = *(const short8*)&Pl[wv][lr16*64 + (((B<<2)+lg)^rx)*8];         \
    acc_l = MFMA(pa, onesf, acc_l);                                            \
    _Pragma("unroll")                                                          \
    for (int db=0;db<4;db++){                                                  \
      int d = db*16 + lr16;                                                    \
      short8 vf = *(const short8*)&Vt[CUR][d*64 + ((((B<<2)+lg)^(d&7))^((d>>3)&7))*8]; \
      O[db] = MFMA(pa, vf, O[db]);                                             \
    }                                                                          \
  }                                                                            \
  __builtin_amdgcn_s_setprio(0);                                               \
  __syncthreads();                                                             \
}while(0)

__global__ __launch_bounds__(512, 4) void k_attn(const u16* __restrict__ qkv,
                                                 u16* __restrict__ o, int T){
  __shared__ __align__(16) u16 Ks[2][64*64];
  __shared__ __align__(16) u16 Vt[2][64*64];
  __shared__ __align__(16) u16 Pl[8][16*64];
  int tid = threadIdx.x, lane = tid&63, wv = tid>>6;
  int bh = blockIdx.x;
  int b = bh>>4, h = bh&15;
  int hq = h*192;
  size_t bt0 = (size_t)b*T;
  int lr16 = lane&15, lg = lane>>4;
  int rx = lr16&7;
  int vr0 = (tid>>4)*2, vd0 = (tid&15)*4;             // V: 2 rows x 4 d per thread
  int kr  = tid>>3;                                    // K: row (512 thr -> 64 rows)
  int kcs = ((tid&7) ^ (kr&7))*8;                      // pre-swizzled source col
  u16x4 va[2];
  const float QS = 0.18033688f;                        // 0.125 * log2(e)
  u16x8 ov;
  #pragma unroll
  for (int j=0;j<8;j++) ov[j] = 0x3F80;                // bf16 1.0
  const short8 onesf = __builtin_bit_cast(short8, ov);

  #pragma unroll 1
  for (int half=0; half<2; ++half){
    int qt = half ? (int)blockIdx.y : 15 - (int)blockIdx.y;
    int qbase = qt*128;
    short8 qf[2];
    {
      const u16* qp = qkv + (bt0 + qbase + wv*16 + lr16)*3072 + hq + lg*8;
      #pragma unroll
      for (int t=0;t<2;t++){
        u16x8 v = *(const u16x8*)(qp + t*32);
        #pragma unroll
        for (int j=0;j<8;j++) v[j] = f2bf(bf2f(v[j])*QS);
        qf[t] = __builtin_bit_cast(short8, v);
      }
    }
    f32x4 O[4] = {};
    f32x4 acc_l = {0,0,0,0};
    float m_run = -1e30f;
    int qglob = qbase + wv*16 + lr16;

    {
      va[0] = *(const u16x4*)(qkv + (bt0 + vr0    )*3072 + hq + 128 + vd0);
      va[1] = *(const u16x4*)(qkv + (bt0 + vr0 + 1)*3072 + hq + 128 + vd0);
      gld_lds16(qkv + (bt0+kr)*3072 + hq + 64 + kcs, &Ks[0][tid*8]);
      #pragma unroll
      for (int k=0;k<4;k++){
        int d = vd0+k;
        int c = (vr0>>3) ^ (d&7) ^ ((d>>3)&7);
        u32 w = (u32)va[0][k] | ((u32)va[1][k]<<16);
        *(u32*)&Vt[0][d*64 + c*8 + (vr0&7)] = w;
      }
    }
    __syncthreads();

    int nkv = 2*qt + 2;   // always even
    #pragma unroll 1
    for (int kb=0; kb<nkv; kb+=2){
      ATTN_ITER(kb,   0, true);
      ATTN_ITER(kb+1, 1, (kb+2<nkv));
    }
    {
      float lrow[4];
      #pragma unroll
      for (int j=0;j<4;j++) lrow[j] = __builtin_amdgcn_rcpf(acc_l[j]);
      #pragma unroll
      for (int db=0;db<4;db++)
        #pragma unroll
        for (int j=0;j<4;j++){
          size_t row = bt0 + qbase + wv*16 + lg*4 + j;
          o[row*1024 + h*64 + db*16 + lr16] = f2bf(O[db][j] * lrow[j]);
        }
    }
  }
}

extern "C" void kernel_launch(void* const* d_in, const int* in_sizes, int n_in,
                              void* d_out, int out_size, void* d_ws, size_t ws_size,
                              hipStream_t stream){
  (void)in_sizes; (void)n_in; (void)out_size; (void)ws_size;
  const float* x     = (const float*)d_in[0];
  const float* Wqkv  = (const float*)d_in[1];
  const float* bqkv  = (const float*)d_in[2];
  const float* Wproj = (const float*)d_in[3];
  const float* bproj = (const float*)d_in[4];
  float* out = (float*)d_out;
  const int B=4, T=2048, C=1024;
  const int M = B*T; // 8192
  char* ws = (char*)d_ws;
  u16* qkvb   = (u16*)(ws);                 // 8192*3072 bf16 = 50331648 B
  u16* attnb  = (u16*)(ws + 50331648);      // 8192*1024 bf16 = 16777216 B
  u16* xb     = (u16*)(ws + 67108864);      // 8192*1024 bf16 = 16777216 B
  u16* wqkvT  = (u16*)(ws + 83886080);      // 3072*1024 bf16 =  6291456 B
  u16* wprojT = (u16*)(ws + 90177536);      // 1024*1024 bf16 =  2097152 B

  k_cast_x<<<4096, 256, 0, stream>>>(x, xb, M*C/8);
  dim3 tb(32,8);
  k_transpose_cast<<<dim3(96,32), tb, 0, stream>>>(Wqkv, wqkvT, C, 3*C);
  k_transpose_cast<<<dim3(32,32), tb, 0, stream>>>(Wproj, wprojT, C, C);
  gemm256<<<dim3(12,32), 512, 131072, stream>>>(xb, wqkvT, bqkv, qkvb, 3*C);
  k_attn<<<dim3(64,8), 512, 0, stream>>>(qkvb, attnb, T);
  gemm_bt<0><<<dim3(8,64), 256, 0, stream>>>(attnb, wprojT, bproj, out, M, C, C);
}

// Round 12
// 183.053 us; speedup vs baseline: 2.6134x; 1.0286x over previous
//
#include <hip/hip_runtime.h>

typedef unsigned short u16;
typedef unsigned int u32;
typedef __attribute__((ext_vector_type(8))) short short8;
typedef __attribute__((ext_vector_type(8))) unsigned short u16x8;
typedef __attribute__((ext_vector_type(4))) unsigned short u16x4;
typedef __attribute__((ext_vector_type(2))) unsigned int u32x2;
typedef __attribute__((ext_vector_type(4))) float f32x4;

__device__ __forceinline__ u16 f2bf(float f){
  u32 u = __builtin_bit_cast(u32, f);
  u32 r = u + 0x7FFFu + ((u >> 16) & 1u);
  return (u16)(r >> 16);
}
__device__ __forceinline__ float bf2f(u16 h){
  u32 u = ((u32)h) << 16;
  return __builtin_bit_cast(float, u);
}
__device__ __forceinline__ float f3max(float a, float b, float c){
  return fmaxf(a, fmaxf(b, c));   // fuses to v_max3_f32
}
__device__ __forceinline__ u32 cvtpk(float lo, float hi){
  u32 r;
  asm("v_cvt_pk_bf16_f32 %0, %1, %2" : "=v"(r) : "v"(lo), "v"(hi));
  return r;
}

__device__ __forceinline__ void gld_lds16(const u16* g, u16* l){
  __builtin_amdgcn_global_load_lds(
      (const __attribute__((address_space(1))) u32*)g,
      (__attribute__((address_space(3))) u32*)l, 16, 0, 0);
}

#define MFMA(a,b,c) __builtin_amdgcn_mfma_f32_16x16x32_bf16((a),(b),(c),0,0,0)

// ---------------- cast x (f32 -> bf16), 8 elems/thread ----------------
__global__ void k_cast_x(const float* __restrict__ in, u16* __restrict__ out, int n8){
  int i = blockIdx.x*256 + threadIdx.x;
  if (i >= n8) return;
  const float4 a = ((const float4*)in)[2*i];
  const float4 b = ((const float4*)in)[2*i+1];
  u16x8 o;
  o[0]=f2bf(a.x); o[1]=f2bf(a.y); o[2]=f2bf(a.z); o[3]=f2bf(a.w);
  o[4]=f2bf(b.x); o[5]=f2bf(b.y); o[6]=f2bf(b.z); o[7]=f2bf(b.w);
  ((u16x8*)out)[i] = o;
}

// ---------------- transpose + cast: in[R][C] f32 -> out[C][R] bf16 ----------------
__global__ void k_transpose_cast(const float* __restrict__ in, u16* __restrict__ out,
                                 int R, int C){
  __shared__ float tile[32][33];
  int c0 = blockIdx.x*32, r0 = blockIdx.y*32;
  int tx = threadIdx.x, ty = threadIdx.y; // block (32,8)
  #pragma unroll
  for (int i=0;i<4;i++) tile[ty+8*i][tx] = in[(size_t)(r0+ty+8*i)*C + c0+tx];
  __syncthreads();
  #pragma unroll
  for (int i=0;i<4;i++) out[(size_t)(c0+ty+8*i)*R + r0+tx] = f2bf(tile[tx][ty+8*i]);
}

// ---------------- 128x256 8-phase GEMM, K=1024: C[M][N] = A[M][1024]*Bt[N][1024]+bias ----------------
// 8 waves (2Mx4N, wave=64x64), BK=64, double-buffered 96KB LDS, T2 swizzle
// (chunk^=row&7, pre-swizzled gld_lds source), per-phase raw barriers +
// setprio MFMA clusters, single vmcnt(0) per K-tile (stages front-loaded).
// QKV: grid (12,64)=768 blocks = 3 rounds/CU. proj: grid (4,64)=256 = 1 round.
#define GS_A(T_, BUF) do{                                                      \
  size_t k0_ = (size_t)(T_)*64;                                                \
  _Pragma("unroll")                                                            \
  for (int l=0;l<2;l++){                                                       \
    int r_ = l*64 + (tid>>3);                                                  \
    gld_lds16(Ag + (size_t)(brow + r_)*1024 + k0_ + (((tid&7)^(r_&7))*8),      \
              &Alds[(BUF)*8192 + l*4096 + tid*8]);                             \
  }                                                                            \
}while(0)

#define GS_B(T_, BUF, H_) do{                                                  \
  size_t k0_ = (size_t)(T_)*64;                                                \
  _Pragma("unroll")                                                            \
  for (int l=0;l<2;l++){                                                       \
    int r_ = (H_)*128 + l*64 + (tid>>3);                                       \
    gld_lds16(Bg + (size_t)(bcol + r_)*1024 + k0_ + (((tid&7)^(r_&7))*8),      \
              &Blds[(BUF)*16384 + (H_)*8192 + l*4096 + tid*8]);                \
  }                                                                            \
}while(0)

#define RD_A(MQ, CUR) do{                                                      \
  _Pragma("unroll")                                                            \
  for (int m=0;m<2;m++)                                                        \
    _Pragma("unroll")                                                          \
    for (int k=0;k<2;k++){                                                     \
      int hr = wr*64 + (MQ)*32 + m*16 + lr16;                                  \
      af[(MQ)*2+m][k] = *(const short8*)&Alds[(CUR)*8192 + hr*64 + (((k*4+lg)^(hr&7))*8)]; \
    }                                                                          \
}while(0)

#define RD_B(NQ, CUR) do{                                                      \
  _Pragma("unroll")                                                            \
  for (int n=0;n<2;n++)                                                        \
    _Pragma("unroll")                                                          \
    for (int k=0;k<2;k++){                                                     \
      int hr = wc*64 + (NQ)*32 + n*16 + lr16;                                  \
      bfv[(NQ)*2+n][k] = *(const short8*)&Blds[(CUR)*16384 + hr*64 + (((k*4+lg)^(hr&7))*8)]; \
    }                                                                          \
}while(0)

#define MF8(MQ, NQ)                                                            \
  _Pragma("unroll")                                                            \
  for (int k=0;k<2;k++)                                                        \
    _Pragma("unroll")                                                          \
    for (int m=0;m<2;m++)                                                      \
      _Pragma("unroll")                                                        \
      for (int n=0;n<2;n++)                                                    \
        acc[(MQ)*2+m][(NQ)*2+n] = MFMA(af[(MQ)*2+m][k], bfv[(NQ)*2+n][k], acc[(MQ)*2+m][(NQ)*2+n]);

#define G_TILE(T_, CUR, PF) do{                                                \
  RD_A(0, CUR); RD_B(0, CUR);                                                  \
  if (PF) GS_A((T_)+1, (CUR)^1);                                               \
  __builtin_amdgcn_s_barrier();                                                \
  __builtin_amdgcn_s_setprio(1); MF8(0,0); __builtin_amdgcn_s_setprio(0);      \
  __builtin_amdgcn_s_barrier();                                                \
  RD_B(1, CUR);                                                                \
  if (PF) GS_B((T_)+1, (CUR)^1, 0);                                            \
  __builtin_amdgcn_s_barrier();                                                \
  __builtin_amdgcn_s_setprio(1); MF8(0,1); __builtin_amdgcn_s_setprio(0);      \
  __builtin_amdgcn_s_barrier();                                                \
  RD_A(1, CUR);                                                                \
  if (PF) GS_B((T_)+1, (CUR)^1, 1);                                            \
  __builtin_amdgcn_s_barrier();                                                \
  __builtin_amdgcn_s_setprio(1); MF8(1,1); __builtin_amdgcn_s_setprio(0);      \
  __builtin_amdgcn_s_barrier();                                                \
  __builtin_amdgcn_s_setprio(1); MF8(1,0); __builtin_amdgcn_s_setprio(0);      \
  asm volatile("s_waitcnt vmcnt(0)" ::: "memory");                             \
  __builtin_amdgcn_sched_barrier(0);                                           \
  __builtin_amdgcn_s_barrier();                                                \
}while(0)

template<int OUT_BF16>
__global__ __launch_bounds__(512, 2) void gemm_ph(const u16* __restrict__ Ag,
                                                  const u16* __restrict__ Bg,
                                                  const float* __restrict__ bias,
                                                  void* __restrict__ Cp, int N){
  extern __shared__ u16 lds[];
  u16* Alds = lds;            // 2 x 8192 elems  (128x64 per buf)
  u16* Blds = lds + 16384;    // 2 x 16384 elems (256x64 per buf)
  int tid = threadIdx.x, lane = tid&63, wid = tid>>6;
  int wr = wid>>2, wc = wid&3;
  int lr16 = lane&15, lg = lane>>4;
  int nbx = gridDim.x;
  int nwg = nbx*gridDim.y;
  int lin = blockIdx.y*nbx + blockIdx.x;
  int cpx = nwg>>3;
  int swz = (lin&7)*cpx + (lin>>3);
  int bx = swz % nbx, by = swz / nbx;
  size_t brow = (size_t)by*128, bcol = (size_t)bx*256;
  f32x4 acc[4][4] = {};
  short8 af[4][2], bfv[4][2];

  GS_A(0, 0);
  GS_B(0, 0, 0);
  GS_B(0, 0, 1);
  __syncthreads();

  #pragma unroll 1
  for (int kt=0; kt<16; kt+=2){
    G_TILE(kt,   0, true);
    G_TILE(kt+1, 1, (kt+2<16));
  }

  #pragma unroll
  for (int ni=0;ni<4;ni++){
    size_t col = bcol + wc*64 + ni*16 + lr16;
    float bs = bias[col];
    #pragma unroll
    for (int mi=0;mi<4;mi++)
      #pragma unroll
      for (int j=0;j<4;j++){
        size_t row = brow + wr*64 + mi*16 + lg*4 + j;
        float v = acc[mi][ni][j] + bs;
        if (OUT_BF16) ((u16*)Cp)[row*(size_t)N + col] = f2bf(v);
        else          ((float*)Cp)[row*(size_t)N + col] = v;
      }
  }
}

// ---------------- flash attention, causal, hs=64, H=16 ----------------
// 8 waves x 512 threads, QBLK=128 (16 q/wave), KVBLK=64. Each block processes
// TWO q-tiles (qt = 15-y then qt = y): 512 equal blocks = 2/CU = 16 waves/CU.
// Double-buffered K/V, async stage split, kv-loop unrolled by 2 (literal CUR).
// Softmax in exp2 domain; defer-max THR=8; l-sum via MFMA ones-trick (acc_l).
#define ATTN_ITER(KB, CUR, PF) do{                                             \
  int kv0 = (KB)*64;                                                           \
  if (PF){                                                                     \
    int kv1 = kv0 + 64;                                                        \
    va[0] = *(const u16x4*)(qkv + (bt0 + kv1 + vr0    )*3072 + hq + 128 + vd0);\
    va[1] = *(const u16x4*)(qkv + (bt0 + kv1 + vr0 + 1)*3072 + hq + 128 + vd0);\
    gld_lds16(qkv + (bt0+kv1+kr)*3072 + hq + 64 + kcs, &Ks[(CUR)^1][tid*8]);   \
  }                                                                            \
  f32x4 st[4];                                                                 \
  __builtin_amdgcn_s_setprio(1);                                               \
  _Pragma("unroll")                                                            \
  for (int s=0;s<4;s++){                                                       \
    short8 kf0 = *(const short8*)&Ks[CUR][(s*16+lr16)*64 + ((lg  )^rx)*8];     \
    short8 kf1 = *(const short8*)&Ks[CUR][(s*16+lr16)*64 + ((4+lg)^rx)*8];     \
    f32x4 z = {0,0,0,0};                                                       \
    z = MFMA(kf0, qf[0], z);                                                   \
    z = MFMA(kf1, qf[1], z);                                                   \
    st[s] = z;                                                                 \
  }                                                                            \
  __builtin_amdgcn_s_setprio(0);                                               \
  if (kv0 >= qbase){                                                           \
    _Pragma("unroll")                                                          \
    for (int s=0;s<4;s++)                                                      \
      _Pragma("unroll")                                                        \
      for (int j=0;j<4;j++){                                                   \
        int kvg = kv0 + s*16 + lg*4 + j;                                       \
        if (kvg > qglob) st[s][j] = -1e30f;                                    \
      }                                                                        \
  }                                                                            \
  {                                                                            \
    float mx = f3max(st[0][0], st[0][1], st[0][2]);                            \
    mx = f3max(mx, st[0][3], st[1][0]);                                        \
    mx = f3max(mx, st[1][1], st[1][2]);                                        \
    mx = f3max(mx, st[1][3], st[2][0]);                                        \
    mx = f3max(mx, st[2][1], st[2][2]);                                        \
    mx = f3max(mx, st[2][3], st[3][0]);                                        \
    mx = f3max(mx, st[3][1], st[3][2]);                                        \
    mx = fmaxf(mx, st[3][3]);                                                  \
    mx = fmaxf(mx, __shfl_xor(mx, 16));                                        \
    mx = fmaxf(mx, __shfl_xor(mx, 32));                                        \
    if (__any(mx > m_run + 8.f)){                                              \
      float m_new = fmaxf(m_run, mx);                                          \
      float al = exp2f(m_run - m_new);                                         \
      m_run = m_new;                                                           \
      float arow[4];                                                           \
      _Pragma("unroll")                                                        \
      for (int j=0;j<4;j++) arow[j] = __shfl(al, lg*4 + j);                    \
      _Pragma("unroll")                                                        \
      for (int db=0;db<4;db++)                                                 \
        _Pragma("unroll")                                                      \
        for (int j=0;j<4;j++) O[db][j] *= arow[j];                             \
      _Pragma("unroll")                                                        \
      for (int j=0;j<4;j++) acc_l[j] *= arow[j];                               \
    }                                                                          \
    float mr = m_run;                                                          \
    u32 pw[8];                                                                 \
    _Pragma("unroll")                                                          \
    for (int s=0;s<4;s++){                                                     \
      float p0 = exp2f(st[s][0]-mr), p1 = exp2f(st[s][1]-mr);                  \
      float p2 = exp2f(st[s][2]-mr), p3 = exp2f(st[s][3]-mr);                  \
      pw[s*2+0] = cvtpk(p0,p1);                                                \
      pw[s*2+1] = cvtpk(p2,p3);                                                \
    }                                                                          \
    _Pragma("unroll")                                                          \
    for (int s=0;s<4;s++){                                                     \
      int cp = (s*2 + (lg>>1)) ^ rx;                                           \
      u32x2 w2; w2[0] = pw[s*2]; w2[1] = pw[s*2+1];                            \
      *(u32x2*)&Pl[wv][lr16*64 + cp*8 + (lg&1)*4] = w2;                        \
    }                                                                          \
  }                                                                            \
  if (PF){                                                                     \
    _Pragma("unroll")                                                          \
    for (int k=0;k<4;k++){                                                     \
      int d = vd0+k;                                                           \
      int c = (vr0>>3) ^ (d&7) ^ ((d>>3)&7);                                   \
      u32 w = (u32)va[0][k] | ((u32)va[1][k]<<16);                             \
      *(u32*)&Vt[(CUR)^1][d*64 + c*8 + (vr0&7)] = w;                           \
    }                                                                          \
  }                                                                            \
  __builtin_amdgcn_s_setprio(1);                                               \
  _Pragma("unroll")                                                            \
  for (int B=0;B<2;B++){                                                       \
    short8 pa = *(const short8*)&Pl[wv][lr16*64 + (((B<<2)+lg)^rx)*8];         \
    acc_l = MFMA(pa, onesf, acc_l);                                            \
    _Pragma("unroll")                                                          \
    for (int db=0;db<4;db++){                                                  \
      int d = db*16 + lr16;                                                    \
      short8 vf = *(const short8*)&Vt[CUR][d*64 + ((((B<<2)+lg)^(d&7))^((d>>3)&7))*8]; \
      O[db] = MFMA(pa, vf, O[db]);                                             \
    }                                                                          \
  }                                                                            \
  __builtin_amdgcn_s_setprio(0);                                               \
  __syncthreads();                                                             \
}while(0)

__global__ __launch_bounds__(512, 4) void k_attn(const u16* __restrict__ qkv,
                                                 u16* __restrict__ o, int T){
  __shared__ __align__(16) u16 Ks[2][64*64];
  __shared__ __align__(16) u16 Vt[2][64*64];
  __shared__ __align__(16) u16 Pl[8][16*64];
  int tid = threadIdx.x, lane = tid&63, wv = tid>>6;
  int bh = blockIdx.x;
  int b = bh>>4, h = bh&15;
  int hq = h*192;
  size_t bt0 = (size_t)b*T;
  int lr16 = lane&15, lg = lane>>4;
  int rx = lr16&7;
  int vr0 = (tid>>4)*2, vd0 = (tid&15)*4;             // V: 2 rows x 4 d per thread
  int kr  = tid>>3;                                    // K: row (512 thr -> 64 rows)
  int kcs = ((tid&7) ^ (kr&7))*8;                      // pre-swizzled source col
  u16x4 va[2];
  const float QS = 0.18033688f;                        // 0.125 * log2(e)
  u16x8 ov;
  #pragma unroll
  for (int j=0;j<8;j++) ov[j] = 0x3F80;                // bf16 1.0
  const short8 onesf = __builtin_bit_cast(short8, ov);

  #pragma unroll 1
  for (int half=0; half<2; ++half){
    int qt = half ? (int)blockIdx.y : 15 - (int)blockIdx.y;
    int qbase = qt*128;
    short8 qf[2];
    {
      const u16* qp = qkv + (bt0 + qbase + wv*16 + lr16)*3072 + hq + lg*8;
      #pragma unroll
      for (int t=0;t<2;t++){
        u16x8 v = *(const u16x8*)(qp + t*32);
        #pragma unroll
        for (int j=0;j<8;j++) v[j] = f2bf(bf2f(v[j])*QS);
        qf[t] = __builtin_bit_cast(short8, v);
      }
    }
    f32x4 O[4] = {};
    f32x4 acc_l = {0,0,0,0};
    float m_run = -1e30f;
    int qglob = qbase + wv*16 + lr16;

    {
      va[0] = *(const u16x4*)(qkv + (bt0 + vr0    )*3072 + hq + 128 + vd0);
      va[1] = *(const u16x4*)(qkv + (bt0 + vr0 + 1)*3072 + hq + 128 + vd0);
      gld_lds16(qkv + (bt0+kr)*3072 + hq + 64 + kcs, &Ks[0][tid*8]);
      #pragma unroll
      for (int k=0;k<4;k++){
        int d = vd0+k;
        int c = (vr0>>3) ^ (d&7) ^ ((d>>3)&7);
        u32 w = (u32)va[0][k] | ((u32)va[1][k]<<16);
        *(u32*)&Vt[0][d*64 + c*8 + (vr0&7)] = w;
      }
    }
    __syncthreads();

    int nkv = 2*qt + 2;   // always even
    #pragma unroll 1
    for (int kb=0; kb<nkv; kb+=2){
      ATTN_ITER(kb,   0, true);
      ATTN_ITER(kb+1, 1, (kb+2<nkv));
    }
    {
      float lrow[4];
      #pragma unroll
      for (int j=0;j<4;j++) lrow[j] = __builtin_amdgcn_rcpf(acc_l[j]);
      #pragma unroll
      for (int db=0;db<4;db++)
        #pragma unroll
        for (int j=0;j<4;j++){
          size_t row = bt0 + qbase + wv*16 + lg*4 + j;
          o[row*1024 + h*64 + db*16 + lr16] = f2bf(O[db][j] * lrow[j]);
        }
    }
  }
}

extern "C" void kernel_launch(void* const* d_in, const int* in_sizes, int n_in,
                              void* d_out, int out_size, void* d_ws, size_t ws_size,
                              hipStream_t stream){
  (void)in_sizes; (void)n_in; (void)out_size; (void)ws_size;
  const float* x     = (const float*)d_in[0];
  const float* Wqkv  = (const float*)d_in[1];
  const float* bqkv  = (const float*)d_in[2];
  const float* Wproj = (const float*)d_in[3];
  const float* bproj = (const float*)d_in[4];
  float* out = (float*)d_out;
  const int B=4, T=2048, C=1024;
  const int M = B*T; // 8192
  char* ws = (char*)d_ws;
  u16* qkvb   = (u16*)(ws);                 // 8192*3072 bf16 = 50331648 B
  u16* attnb  = (u16*)(ws + 50331648);      // 8192*1024 bf16 = 16777216 B
  u16* xb     = (u16*)(ws + 67108864);      // 8192*1024 bf16 = 16777216 B
  u16* wqkvT  = (u16*)(ws + 83886080);      // 3072*1024 bf16 =  6291456 B
  u16* wprojT = (u16*)(ws + 90177536);      // 1024*1024 bf16 =  2097152 B

  k_cast_x<<<4096, 256, 0, stream>>>(x, xb, M*C/8);
  dim3 tb(32,8);
  k_transpose_cast<<<dim3(96,32), tb, 0, stream>>>(Wqkv, wqkvT, C, 3*C);
  k_transpose_cast<<<dim3(32,32), tb, 0, stream>>>(Wproj, wprojT, C, C);
  gemm_ph<1><<<dim3(12,64), 512, 98304, stream>>>(xb, wqkvT, bqkv, qkvb, 3*C);
  k_attn<<<dim3(64,8), 512, 0, stream>>>(qkvb, attnb, T);
  gemm_ph<0><<<dim3(4,64), 512, 98304, stream>>>(attnb, wprojT, bproj, out, C);
}